// Round 1
// baseline (7359.547 us; speedup 1.0000x reference)
//
#include <hip/hip_runtime.h>
#include <cmath>

// ---------------- problem constants ----------------
constexpr int IMH = 320, IMW = 320, NPIX = IMH * IMW, NC = 21;
constexpr int DB = 5, DB1 = 6;   // bilateral lattice dim
constexpr int DS = 2, DS1 = 3;   // spatial lattice dim
constexpr int RB = NPIX * DB1;   // max lattice points / splat entries (bilateral)
constexpr int RS = NPIX * DS1;   // (spatial)
constexpr int TBS = 1 << 21;     // hash table slots (bilateral), load <= 0.3
constexpr int TSS = 1 << 20;     // hash table slots (spatial)

#define EMPTY_KEY 0xFFFFFFFFFFFFFFFFULL

__device__ __forceinline__ unsigned long long mix64(unsigned long long x) {
    x ^= x >> 33; x *= 0xff51afd7ed558ccdULL;
    x ^= x >> 33; x *= 0xc4ceb9fe1a85ec53ULL;
    x ^= x >> 33; return x;
}

// ---------------- permutohedral embedding (matches reference op-for-op, f32) ----------------
template<int D>
__device__ void perm_embed(const float* f, float* bary, unsigned long long* pk) {
    constexpr int D1 = D + 1;
    float cf[D];
    #pragma unroll
    for (int i = 0; i < D; i++) {
        double s = sqrt(2.0 / 3.0) * (double)D1 / sqrt((double)((i + 1) * (i + 2)));
        cf[i] = f[i] * (float)s;
    }
    float csum[D];
    float acc = 0.f;
    #pragma unroll
    for (int i = D - 1; i >= 0; i--) { acc += cf[i]; csum[i] = acc; }
    float el[D1];
    el[0] = csum[0];
    #pragma unroll
    for (int i = 1; i < D; i++) el[i] = csum[i] - (float)i * cf[i - 1];
    el[D] = -(float)D * cf[D - 1];
    const float down = 1.0f / (float)D1;
    float rem0[D1]; int rank[D1]; int ssum = 0;
    #pragma unroll
    for (int i = 0; i < D1; i++) {
        float rd = rintf(el[i] * down);
        rem0[i] = rd * (float)D1;
        ssum += (int)rd;
    }
    float diff[D1];
    #pragma unroll
    for (int i = 0; i < D1; i++) diff[i] = el[i] - rem0[i];
    #pragma unroll
    for (int i = 0; i < D1; i++) {
        int r = 0;
        #pragma unroll
        for (int j = 0; j < D1; j++)
            r += (diff[j] > diff[i]) || ((diff[j] == diff[i]) && (j < i));
        rank[i] = r + ssum;
    }
    #pragma unroll
    for (int i = 0; i < D1; i++) {
        if (rank[i] < 0)      { rank[i] += D1; rem0[i] += (float)D1; }
        else if (rank[i] > D) { rank[i] -= D1; rem0[i] -= (float)D1; }
    }
    float b[D + 2];
    #pragma unroll
    for (int i = 0; i < D + 2; i++) b[i] = 0.f;
    #pragma unroll
    for (int i = 0; i < D1; i++) b[D - rank[i]]     += (el[i] - rem0[i]) * down;
    #pragma unroll
    for (int i = 0; i < D1; i++) b[D + 1 - rank[i]] -= (el[i] - rem0[i]) * down;
    b[0] += 1.0f + b[D + 1];
    #pragma unroll
    for (int i = 0; i < D1; i++) bary[i] = b[i];
    int key0[D];
    #pragma unroll
    for (int i = 0; i < D; i++) key0[i] = (int)rintf(rem0[i]);
    #pragma unroll
    for (int r = 0; r < D1; r++) {
        unsigned long long p = 0;
        #pragma unroll
        for (int i = 0; i < D; i++) {
            int c = key0[i] + ((rank[i] < D1 - r) ? r : r - D1);
            p |= ((unsigned long long)((unsigned)(c + 2048) & 0xFFFu)) << (12 * i);
        }
        pk[r] = p;
    }
}

// ---------------- hash table ----------------
__device__ __forceinline__ int hash_insert(unsigned long long* hk, int tmask, unsigned long long k) {
    int slot = (int)(mix64(k) & (unsigned long long)tmask);
    while (true) {
        unsigned long long prev = atomicCAS(&hk[slot], EMPTY_KEY, k);
        if (prev == EMPTY_KEY || prev == k) return slot;
        slot = (slot + 1) & tmask;
    }
}
__device__ __forceinline__ int hash_lookup(const unsigned long long* hk, const int* hid,
                                           int tmask, unsigned long long k) {
    int slot = (int)(mix64(k) & (unsigned long long)tmask);
    while (true) {
        unsigned long long v = hk[slot];
        if (v == k) return hid[slot];
        if (v == EMPTY_KEY) return -1;
        slot = (slot + 1) & tmask;
    }
}

// ---------------- build kernels ----------------
__global__ void build_bilateral(const float* __restrict__ image, unsigned long long* hk,
                                int tmask, int* os, float* wsv) {
    int i = blockIdx.x * blockDim.x + threadIdx.x;
    if (i >= NPIX) return;
    int x = i % IMW, y = i / IMW;
    float f[DB];
    f[0] = (float)x / 80.0f;           // THETA_ALPHA
    f[1] = (float)y / 80.0f;
    f[2] = image[i * 3 + 0] / 13.0f;   // THETA_BETA
    f[3] = image[i * 3 + 1] / 13.0f;
    f[4] = image[i * 3 + 2] / 13.0f;
    float bary[DB1]; unsigned long long pk[DB1];
    perm_embed<DB>(f, bary, pk);
    #pragma unroll
    for (int r = 0; r < DB1; r++) {
        wsv[i * DB1 + r] = bary[r];
        os[i * DB1 + r] = hash_insert(hk, tmask, pk[r]);  // slot; remapped to id later
    }
}

__global__ void build_spatial(unsigned long long* hk, int tmask, int* os, float* wsv) {
    int i = blockIdx.x * blockDim.x + threadIdx.x;
    if (i >= NPIX) return;
    int x = i % IMW, y = i / IMW;
    float f[DS];
    f[0] = (float)x / 3.0f;            // THETA_GAMMA
    f[1] = (float)y / 3.0f;
    float bary[DS1]; unsigned long long pk[DS1];
    perm_embed<DS>(f, bary, pk);
    #pragma unroll
    for (int r = 0; r < DS1; r++) {
        wsv[i * DS1 + r] = bary[r];
        os[i * DS1 + r] = hash_insert(hk, tmask, pk[r]);
    }
}

__global__ void compact_kernel(const unsigned long long* hk, int T, int* hid,
                               unsigned long long* uk, int* cnt) {
    int s = blockIdx.x * blockDim.x + threadIdx.x;
    if (s >= T) return;
    unsigned long long k = hk[s];
    if (k != EMPTY_KEY) {
        int id = atomicAdd(cnt, 1);
        hid[s] = id;
        uk[id] = k;
    }
}

__global__ void os_finalize(int* os, const int* hid, int R) {
    int i = blockIdx.x * blockDim.x + threadIdx.x;
    if (i < R) os[i] = hid[os[i]];
}

template<int D>
__global__ void build_neighbors(const unsigned long long* uk, const unsigned long long* hk,
                                const int* hid, int tmask, const int* cnt, int stride,
                                int* n1, int* n2) {
    int m = blockIdx.x * blockDim.x + threadIdx.x;
    if (m >= *cnt) return;
    unsigned long long k = uk[m];
    int c[D];
    #pragma unroll
    for (int i = 0; i < D; i++) c[i] = (int)((k >> (12 * i)) & 0xFFFULL) - 2048;
    for (int j = 0; j <= D; j++) {
        unsigned long long p1 = 0, p2 = 0;
        #pragma unroll
        for (int i = 0; i < D; i++) {
            int a = c[i] + ((i == j) ? D : -1);   // key - 1 + (D+1)*e_j
            int b = c[i] + ((i == j) ? -D : 1);   // key + 1 - (D+1)*e_j
            p1 |= ((unsigned long long)((unsigned)(a + 2048) & 0xFFFu)) << (12 * i);
            p2 |= ((unsigned long long)((unsigned)(b + 2048) & 0xFFFu)) << (12 * i);
        }
        n1[j * stride + m] = hash_lookup(hk, hid, tmask, p1);
        n2[j * stride + m] = hash_lookup(hk, hid, tmask, p2);
    }
}

// ---------------- filter kernels ----------------
template<int CC>
__global__ void zero_buf(float* buf, const int* cnt) {
    int idx = blockIdx.x * blockDim.x + threadIdx.x;
    int total = (*cnt + 1) * CC;
    if (idx < total) buf[idx] = 0.f;
}

template<int CC, int D1>
__global__ void splat(const float* __restrict__ vals, const int* __restrict__ os,
                      const float* __restrict__ wsv, float* buf, int R) {
    int idx = blockIdx.x * blockDim.x + threadIdx.x;
    if (idx >= R) return;
    int i = idx / D1;
    int o = os[idx]; float w = wsv[idx];
    float* dst = buf + (size_t)(o + 1) * CC;
    const float* src = vals + (size_t)i * CC;
    #pragma unroll
    for (int c = 0; c < CC; c++) atomicAdd(dst + c, w * src[c]);
}

template<int D1>
__global__ void splat_ones(const int* __restrict__ os, const float* __restrict__ wsv,
                           float* buf, int R) {
    int idx = blockIdx.x * blockDim.x + threadIdx.x;
    if (idx >= R) return;
    atomicAdd(buf + os[idx] + 1, wsv[idx]);
}

template<int CC>
__global__ void blur_step(const float* __restrict__ in, float* __restrict__ out,
                          const int* __restrict__ n1, const int* __restrict__ n2,
                          const int* cnt) {
    int idx = blockIdx.x * blockDim.x + threadIdx.x;
    int M = *cnt;
    if (idx >= (M + 1) * CC) return;
    int row = idx / CC, c = idx - row * CC;
    if (row == 0) { out[idx] = 0.f; return; }  // zero row = missing-neighbor sink
    int m = row - 1;
    float a = in[(n1[m] + 1) * CC + c];
    float b = in[(n2[m] + 1) * CC + c];
    out[idx] = in[idx] + 0.5f * (a + b);
}

template<int CC, int D1>
__global__ void slice_k(const float* __restrict__ buf, const int* __restrict__ os,
                        const float* __restrict__ wsv, float* __restrict__ out, float alpha) {
    int idx = blockIdx.x * blockDim.x + threadIdx.x;
    if (idx >= NPIX * CC) return;
    int i = idx / CC, c = idx - i * CC;
    float s = 0.f;
    #pragma unroll
    for (int r = 0; r < D1; r++)
        s += wsv[i * D1 + r] * buf[(os[i * D1 + r] + 1) * CC + c];
    out[idx] = alpha * s;
}

template<int D1>
__global__ void slice_norm(const float* __restrict__ buf, const int* __restrict__ os,
                           const float* __restrict__ wsv, float* normv, float alpha) {
    int i = blockIdx.x * blockDim.x + threadIdx.x;
    if (i >= NPIX) return;
    float s = 0.f;
    #pragma unroll
    for (int r = 0; r < D1; r++)
        s += wsv[i * D1 + r] * buf[os[i * D1 + r] + 1];
    normv[i] = alpha * s + 1e-20f;
}

__global__ void update_q(const float* __restrict__ U, const float* __restrict__ fb,
                         const float* __restrict__ fs, const float* __restrict__ nb,
                         const float* __restrict__ ns, float* __restrict__ Q, int use_msg) {
    int i = blockIdx.x * blockDim.x + threadIdx.x;
    if (i >= NPIX) return;
    float l[NC];
    float mx = -1e30f;
    float inb = 1.f, ins = 1.f;
    if (use_msg) { inb = nb[i]; ins = ns[i]; }
    #pragma unroll
    for (int c = 0; c < NC; c++) {
        float v = -U[i * NC + c];
        if (use_msg)
            v += 10.0f * (fb[i * NC + c] / inb) + 3.0f * (fs[i * NC + c] / ins);
        l[c] = v; mx = fmaxf(mx, v);
    }
    float s = 0.f;
    #pragma unroll
    for (int c = 0; c < NC; c++) { float e = expf(l[c] - mx); l[c] = e; s += e; }
    #pragma unroll
    for (int c = 0; c < NC; c++) Q[i * NC + c] = l[c] / s;
}

// ---------------- host orchestration ----------------
extern "C" void kernel_launch(void* const* d_in, const int* in_sizes, int n_in,
                              void* d_out, int out_size, void* d_ws, size_t ws_size,
                              hipStream_t stream) {
    const float* U     = (const float*)d_in[0];  // (N, 21)
    const float* image = (const float*)d_in[1];  // (N, 3)
    float* Q = (float*)d_out;                    // Q buffer lives in d_out

    char* base = (char*)d_ws;
    size_t off = 0;
    auto alloc = [&](size_t bytes) -> void* {
        off = (off + 255) & ~(size_t)255;
        void* p = base + off; off += bytes; return p;
    };
    int*   os_b = (int*)  alloc((size_t)RB * 4);
    float* ws_b = (float*)alloc((size_t)RB * 4);
    int*   n1_b = (int*)  alloc((size_t)DB1 * RB * 4);
    int*   n2_b = (int*)  alloc((size_t)DB1 * RB * 4);
    unsigned long long* uk_b = (unsigned long long*)alloc((size_t)RB * 8);
    int*   os_s = (int*)  alloc((size_t)RS * 4);
    float* ws_s = (float*)alloc((size_t)RS * 4);
    int*   n1_s = (int*)  alloc((size_t)DS1 * RS * 4);
    int*   n2_s = (int*)  alloc((size_t)DS1 * RS * 4);
    unsigned long long* uk_s = (unsigned long long*)alloc((size_t)RS * 8);
    unsigned long long* hk = (unsigned long long*)alloc((size_t)TBS * 8);
    int*   hid  = (int*)  alloc((size_t)TBS * 4);
    int*   cnt  = (int*)  alloc(256);            // cnt[0]=M_bilateral, cnt[1]=M_spatial
    float* norm_b = (float*)alloc((size_t)NPIX * 4);
    float* norm_s = (float*)alloc((size_t)NPIX * 4);
    float* fb   = (float*)alloc((size_t)NPIX * NC * 4);
    float* fs   = (float*)alloc((size_t)NPIX * NC * 4);
    float* buf0 = (float*)alloc((size_t)(RB + 1) * NC * 4);
    float* buf1 = (float*)alloc((size_t)(RB + 1) * NC * 4);
    if (off > ws_size) return;  // insufficient scratch -> visible as validation failure

    const float ALPHA_B = (float)(1.0 / (1.0 + exp2(-(double)DB)));  // 32/33
    const float ALPHA_S = (float)(1.0 / (1.0 + exp2(-(double)DS)));  // 4/5

    // ---- build bilateral lattice ----
    hipMemsetAsync(hk, 0xFF, (size_t)TBS * 8, stream);
    hipMemsetAsync(cnt, 0, 8, stream);
    build_bilateral<<<(NPIX + 255) / 256, 256, 0, stream>>>(image, hk, TBS - 1, os_b, ws_b);
    compact_kernel<<<TBS / 256, 256, 0, stream>>>(hk, TBS, hid, uk_b, cnt + 0);
    os_finalize<<<(RB + 255) / 256, 256, 0, stream>>>(os_b, hid, RB);
    build_neighbors<DB><<<(RB + 255) / 256, 256, 0, stream>>>(uk_b, hk, hid, TBS - 1, cnt + 0, RB, n1_b, n2_b);

    // ---- build spatial lattice (reuse hash region) ----
    hipMemsetAsync(hk, 0xFF, (size_t)TSS * 8, stream);
    build_spatial<<<(NPIX + 255) / 256, 256, 0, stream>>>(hk, TSS - 1, os_s, ws_s);
    compact_kernel<<<TSS / 256, 256, 0, stream>>>(hk, TSS, hid, uk_s, cnt + 1);
    os_finalize<<<(RS + 255) / 256, 256, 0, stream>>>(os_s, hid, RS);
    build_neighbors<DS><<<(RS + 255) / 256, 256, 0, stream>>>(uk_s, hk, hid, TSS - 1, cnt + 1, RS, n1_s, n2_s);

    // ---- norm filters (C=1), computed once ----
    {
        zero_buf<1><<<(RB + 1 + 255) / 256, 256, 0, stream>>>(buf0, cnt + 0);
        splat_ones<DB1><<<(RB + 255) / 256, 256, 0, stream>>>(os_b, ws_b, buf0, RB);
        float* a = buf0; float* b = buf1;
        for (int j = 0; j < DB1; j++) {
            blur_step<1><<<(RB + 1 + 255) / 256, 256, 0, stream>>>(a, b, n1_b + (size_t)j * RB, n2_b + (size_t)j * RB, cnt + 0);
            float* t = a; a = b; b = t;
        }
        slice_norm<DB1><<<(NPIX + 255) / 256, 256, 0, stream>>>(a, os_b, ws_b, norm_b, ALPHA_B);

        zero_buf<1><<<(RS + 1 + 255) / 256, 256, 0, stream>>>(buf0, cnt + 1);
        splat_ones<DS1><<<(RS + 255) / 256, 256, 0, stream>>>(os_s, ws_s, buf0, RS);
        a = buf0; b = buf1;
        for (int j = 0; j < DS1; j++) {
            blur_step<1><<<(RS + 1 + 255) / 256, 256, 0, stream>>>(a, b, n1_s + (size_t)j * RS, n2_s + (size_t)j * RS, cnt + 1);
            float* t = a; a = b; b = t;
        }
        slice_norm<DS1><<<(NPIX + 255) / 256, 256, 0, stream>>>(a, os_s, ws_s, norm_s, ALPHA_S);
    }

    // ---- Q0 = softmax(-U) ----
    update_q<<<(NPIX + 255) / 256, 256, 0, stream>>>(U, fb, fs, norm_b, norm_s, Q, 0);

    // ---- 5 mean-field iterations ----
    for (int it = 0; it < 5; it++) {
        // bilateral filter of Q -> fb
        zero_buf<NC><<<((RB + 1) * NC + 255) / 256, 256, 0, stream>>>(buf0, cnt + 0);
        splat<NC, DB1><<<(RB + 255) / 256, 256, 0, stream>>>(Q, os_b, ws_b, buf0, RB);
        float* a = buf0; float* b = buf1;
        for (int j = 0; j < DB1; j++) {
            blur_step<NC><<<((RB + 1) * NC + 255) / 256, 256, 0, stream>>>(a, b, n1_b + (size_t)j * RB, n2_b + (size_t)j * RB, cnt + 0);
            float* t = a; a = b; b = t;
        }
        slice_k<NC, DB1><<<(NPIX * NC + 255) / 256, 256, 0, stream>>>(a, os_b, ws_b, fb, ALPHA_B);

        // spatial filter of Q -> fs
        zero_buf<NC><<<((RS + 1) * NC + 255) / 256, 256, 0, stream>>>(buf0, cnt + 1);
        splat<NC, DS1><<<(RS + 255) / 256, 256, 0, stream>>>(Q, os_s, ws_s, buf0, RS);
        a = buf0; b = buf1;
        for (int j = 0; j < DS1; j++) {
            blur_step<NC><<<((RS + 1) * NC + 255) / 256, 256, 0, stream>>>(a, b, n1_s + (size_t)j * RS, n2_s + (size_t)j * RS, cnt + 1);
            float* t = a; a = b; b = t;
        }
        slice_k<NC, DS1><<<(NPIX * NC + 255) / 256, 256, 0, stream>>>(a, os_s, ws_s, fs, ALPHA_S);

        // Q = softmax(-U + 10*fb/norm_b + 3*fs/norm_s)
        update_q<<<(NPIX + 255) / 256, 256, 0, stream>>>(U, fb, fs, norm_b, norm_s, Q, 1);
    }
}

// Round 2
// 1715.875 us; speedup vs baseline: 4.2891x; 4.2891x over previous
//
#include <hip/hip_runtime.h>
#include <cmath>

// ---------------- problem constants ----------------
constexpr int IMH = 320, IMW = 320, NPIX = IMH * IMW, NC = 21;
constexpr int DB = 5, DB1 = 6;   // bilateral lattice dim
constexpr int DS = 2, DS1 = 3;   // spatial lattice dim
constexpr int RB = NPIX * DB1;   // splat entries (bilateral) = 614400
constexpr int RS = NPIX * DS1;   // (spatial) = 307200
constexpr int TBS = 1 << 20;     // hash table slots (bilateral), load <= 0.6
constexpr int TSS = 1 << 20;     // hash table slots (spatial)

#define EMPTY_KEY 0xFFFFFFFFFFFFFFFFULL

__device__ __forceinline__ unsigned long long mix64(unsigned long long x) {
    x ^= x >> 33; x *= 0xff51afd7ed558ccdULL;
    x ^= x >> 33; x *= 0xc4ceb9fe1a85ec53ULL;
    x ^= x >> 33; return x;
}

// ---------------- permutohedral embedding (matches reference op-for-op, f32) ----------------
template<int D>
__device__ void perm_embed(const float* f, float* bary, unsigned long long* pk) {
    constexpr int D1 = D + 1;
    float cf[D];
    #pragma unroll
    for (int i = 0; i < D; i++) {
        double s = sqrt(2.0 / 3.0) * (double)D1 / sqrt((double)((i + 1) * (i + 2)));
        cf[i] = f[i] * (float)s;
    }
    float csum[D];
    float acc = 0.f;
    #pragma unroll
    for (int i = D - 1; i >= 0; i--) { acc += cf[i]; csum[i] = acc; }
    float el[D1];
    el[0] = csum[0];
    #pragma unroll
    for (int i = 1; i < D; i++) el[i] = csum[i] - (float)i * cf[i - 1];
    el[D] = -(float)D * cf[D - 1];
    const float down = 1.0f / (float)D1;
    float rem0[D1]; int rank[D1]; int ssum = 0;
    #pragma unroll
    for (int i = 0; i < D1; i++) {
        float rd = rintf(el[i] * down);
        rem0[i] = rd * (float)D1;
        ssum += (int)rd;
    }
    float diff[D1];
    #pragma unroll
    for (int i = 0; i < D1; i++) diff[i] = el[i] - rem0[i];
    #pragma unroll
    for (int i = 0; i < D1; i++) {
        int r = 0;
        #pragma unroll
        for (int j = 0; j < D1; j++)
            r += (diff[j] > diff[i]) || ((diff[j] == diff[i]) && (j < i));
        rank[i] = r + ssum;
    }
    #pragma unroll
    for (int i = 0; i < D1; i++) {
        if (rank[i] < 0)      { rank[i] += D1; rem0[i] += (float)D1; }
        else if (rank[i] > D) { rank[i] -= D1; rem0[i] -= (float)D1; }
    }
    float b[D + 2];
    #pragma unroll
    for (int i = 0; i < D + 2; i++) b[i] = 0.f;
    #pragma unroll
    for (int i = 0; i < D1; i++) b[D - rank[i]]     += (el[i] - rem0[i]) * down;
    #pragma unroll
    for (int i = 0; i < D1; i++) b[D + 1 - rank[i]] -= (el[i] - rem0[i]) * down;
    b[0] += 1.0f + b[D + 1];
    #pragma unroll
    for (int i = 0; i < D1; i++) bary[i] = b[i];
    int key0[D];
    #pragma unroll
    for (int i = 0; i < D; i++) key0[i] = (int)rintf(rem0[i]);
    #pragma unroll
    for (int r = 0; r < D1; r++) {
        unsigned long long p = 0;
        #pragma unroll
        for (int i = 0; i < D; i++) {
            int c = key0[i] + ((rank[i] < D1 - r) ? r : r - D1);
            p |= ((unsigned long long)((unsigned)(c + 2048) & 0xFFFu)) << (12 * i);
        }
        pk[r] = p;
    }
}

// ---------------- hash table ----------------
__device__ __forceinline__ int hash_insert(unsigned long long* hk, int tmask, unsigned long long k) {
    int slot = (int)(mix64(k) & (unsigned long long)tmask);
    while (true) {
        unsigned long long prev = atomicCAS(&hk[slot], EMPTY_KEY, k);
        if (prev == EMPTY_KEY || prev == k) return slot;
        slot = (slot + 1) & tmask;
    }
}
__device__ __forceinline__ int hash_lookup(const unsigned long long* hk, const int* hid,
                                           int tmask, unsigned long long k) {
    int slot = (int)(mix64(k) & (unsigned long long)tmask);
    while (true) {
        unsigned long long v = hk[slot];
        if (v == k) return hid[slot];
        if (v == EMPTY_KEY) return -1;
        slot = (slot + 1) & tmask;
    }
}

// ---------------- build kernels ----------------
__global__ void build_bilateral(const float* __restrict__ image, unsigned long long* hk,
                                int tmask, int* os, float* wsv) {
    int i = blockIdx.x * blockDim.x + threadIdx.x;
    if (i >= NPIX) return;
    int x = i % IMW, y = i / IMW;
    float f[DB];
    f[0] = (float)x / 80.0f;           // THETA_ALPHA
    f[1] = (float)y / 80.0f;
    f[2] = image[i * 3 + 0] / 13.0f;   // THETA_BETA
    f[3] = image[i * 3 + 1] / 13.0f;
    f[4] = image[i * 3 + 2] / 13.0f;
    float bary[DB1]; unsigned long long pk[DB1];
    perm_embed<DB>(f, bary, pk);
    #pragma unroll
    for (int r = 0; r < DB1; r++) {
        wsv[i * DB1 + r] = bary[r];
        os[i * DB1 + r] = hash_insert(hk, tmask, pk[r]);  // slot; remapped to id later
    }
}

__global__ void build_spatial(unsigned long long* hk, int tmask, int* os, float* wsv) {
    int i = blockIdx.x * blockDim.x + threadIdx.x;
    if (i >= NPIX) return;
    int x = i % IMW, y = i / IMW;
    float f[DS];
    f[0] = (float)x / 3.0f;            // THETA_GAMMA
    f[1] = (float)y / 3.0f;
    float bary[DS1]; unsigned long long pk[DS1];
    perm_embed<DS>(f, bary, pk);
    #pragma unroll
    for (int r = 0; r < DS1; r++) {
        wsv[i * DS1 + r] = bary[r];
        os[i * DS1 + r] = hash_insert(hk, tmask, pk[r]);
    }
}

__global__ void compact_kernel(const unsigned long long* hk, int T, int* hid,
                               unsigned long long* uk, int* cnt) {
    int s = blockIdx.x * blockDim.x + threadIdx.x;
    if (s >= T) return;
    unsigned long long k = hk[s];
    if (k != EMPTY_KEY) {
        int id = atomicAdd(cnt, 1);
        hid[s] = id;
        uk[id] = k;
    }
}

__global__ void os_finalize(int* os, const int* hid, int R) {
    int i = blockIdx.x * blockDim.x + threadIdx.x;
    if (i < R) os[i] = hid[os[i]];
}

template<int D>
__global__ void build_neighbors(const unsigned long long* uk, const unsigned long long* hk,
                                const int* hid, int tmask, const int* cnt, int stride,
                                int* n1, int* n2) {
    int m = blockIdx.x * blockDim.x + threadIdx.x;
    if (m >= *cnt) return;
    unsigned long long k = uk[m];
    int c[D];
    #pragma unroll
    for (int i = 0; i < D; i++) c[i] = (int)((k >> (12 * i)) & 0xFFFULL) - 2048;
    for (int j = 0; j <= D; j++) {
        unsigned long long p1 = 0, p2 = 0;
        #pragma unroll
        for (int i = 0; i < D; i++) {
            int a = c[i] + ((i == j) ? D : -1);   // key - 1 + (D+1)*e_j
            int b = c[i] + ((i == j) ? -D : 1);   // key + 1 - (D+1)*e_j
            p1 |= ((unsigned long long)((unsigned)(a + 2048) & 0xFFFu)) << (12 * i);
            p2 |= ((unsigned long long)((unsigned)(b + 2048) & 0xFFFu)) << (12 * i);
        }
        n1[j * stride + m] = hash_lookup(hk, hid, tmask, p1);
        n2[j * stride + m] = hash_lookup(hk, hid, tmask, p2);
    }
}

// ---------------- inverted-index build (splat -> gather) ----------------
__global__ void count_entries(const int* __restrict__ os, int* count, int R) {
    int i = blockIdx.x * blockDim.x + threadIdx.x;
    if (i < R) atomicAdd(&count[os[i]], 1);
}

// per-256-block inclusive scan; incl written in place of off[], block totals to bsums
__global__ void scan_block(const int* __restrict__ count, int* incl, int* bsums, int Mcap) {
    __shared__ int sh[256];
    int idx = blockIdx.x * 256 + threadIdx.x;
    int v = (idx < Mcap) ? count[idx] : 0;
    sh[threadIdx.x] = v;
    __syncthreads();
    for (int d = 1; d < 256; d <<= 1) {
        int t = (threadIdx.x >= d) ? sh[threadIdx.x - d] : 0;
        __syncthreads();
        sh[threadIdx.x] += t;
        __syncthreads();
    }
    if (idx < Mcap) incl[idx] = sh[threadIdx.x];
    if (threadIdx.x == 255) bsums[blockIdx.x] = sh[255];
}

// single-block exclusive scan of block sums (in place)
__global__ void scan_bsums(int* bsums, int nb) {
    __shared__ int sh[256];
    __shared__ int run;
    if (threadIdx.x == 0) run = 0;
    __syncthreads();
    for (int base = 0; base < nb; base += 256) {
        int idx = base + threadIdx.x;
        int v = (idx < nb) ? bsums[idx] : 0;
        sh[threadIdx.x] = v;
        __syncthreads();
        for (int d = 1; d < 256; d <<= 1) {
            int t = (threadIdx.x >= d) ? sh[threadIdx.x - d] : 0;
            __syncthreads();
            sh[threadIdx.x] += t;
            __syncthreads();
        }
        int total = sh[255];
        int excl = sh[threadIdx.x] - v + run;
        if (idx < nb) bsums[idx] = excl;
        __syncthreads();
        if (threadIdx.x == 0) run += total;
        __syncthreads();
    }
}

// off[idx] = incl[idx] - count[idx] + bsums[idx/256]   (turn incl -> global exclusive)
__global__ void finalize_off(int* off, const int* __restrict__ count,
                             const int* __restrict__ bsums, int Mcap) {
    int idx = blockIdx.x * 256 + threadIdx.x;
    if (idx < Mcap) off[idx] = off[idx] - count[idx] + bsums[blockIdx.x];
}

__global__ void fill_entries(const int* __restrict__ os, const float* __restrict__ wsv,
                             const int* __restrict__ off, int* fill,
                             int* ep, float* ew, int R, int D1) {
    int idx = blockIdx.x * blockDim.x + threadIdx.x;
    if (idx >= R) return;
    int m = os[idx];
    int pos = off[m] + atomicAdd(&fill[m], 1);
    ep[pos] = idx / D1;     // pixel index
    ew[pos] = wsv[idx];
}

// ---------------- filter kernels ----------------
// gather splat: buf[0][*]=0 (sink row); buf[m+1][c] = sum_t ew[t]*vals[ep[t]*CC+c]
template<int CC>
__global__ void gather_splat(const float* __restrict__ vals, const int* __restrict__ off,
                             const int* __restrict__ count, const int* __restrict__ ep,
                             const float* __restrict__ ew, float* __restrict__ buf,
                             const int* cnt) {
    int M = *cnt;
    int total = (M + 1) * CC;
    int stride = gridDim.x * blockDim.x;
    for (int idx = blockIdx.x * blockDim.x + threadIdx.x; idx < total; idx += stride) {
        int row = idx / CC, c = idx - row * CC;
        if (row == 0) { buf[idx] = 0.f; continue; }
        int m = row - 1;
        int s = off[m], e = s + count[m];
        float acc = 0.f;
        for (int t = s; t < e; t++)
            acc += ew[t] * vals[(size_t)ep[t] * CC + c];
        buf[idx] = acc;
    }
}

// C=1 norm splat: just the sum of weights per row
__global__ void gather_splat1(const int* __restrict__ off, const int* __restrict__ count,
                              const float* __restrict__ ew, float* __restrict__ buf,
                              const int* cnt) {
    int M = *cnt;
    int stride = gridDim.x * blockDim.x;
    for (int row = blockIdx.x * blockDim.x + threadIdx.x; row <= M; row += stride) {
        if (row == 0) { buf[0] = 0.f; continue; }
        int m = row - 1;
        int s = off[m], e = s + count[m];
        float acc = 0.f;
        for (int t = s; t < e; t++) acc += ew[t];
        buf[row] = acc;
    }
}

template<int CC>
__global__ void blur_step(const float* __restrict__ in, float* __restrict__ out,
                          const int* __restrict__ n1, const int* __restrict__ n2,
                          const int* cnt) {
    int M = *cnt;
    int total = (M + 1) * CC;
    int stride = gridDim.x * blockDim.x;
    for (int idx = blockIdx.x * blockDim.x + threadIdx.x; idx < total; idx += stride) {
        int row = idx / CC, c = idx - row * CC;
        if (row == 0) { out[idx] = 0.f; continue; }  // zero row = missing-neighbor sink
        int m = row - 1;
        float a = in[(n1[m] + 1) * CC + c];
        float b = in[(n2[m] + 1) * CC + c];
        out[idx] = in[idx] + 0.5f * (a + b);
    }
}

template<int CC, int D1>
__global__ void slice_k(const float* __restrict__ buf, const int* __restrict__ os,
                        const float* __restrict__ wsv, float* __restrict__ out, float alpha) {
    int idx = blockIdx.x * blockDim.x + threadIdx.x;
    if (idx >= NPIX * CC) return;
    int i = idx / CC, c = idx - i * CC;
    float s = 0.f;
    #pragma unroll
    for (int r = 0; r < D1; r++)
        s += wsv[i * D1 + r] * buf[(os[i * D1 + r] + 1) * CC + c];
    out[idx] = alpha * s;
}

template<int D1>
__global__ void slice_norm(const float* __restrict__ buf, const int* __restrict__ os,
                           const float* __restrict__ wsv, float* normv, float alpha) {
    int i = blockIdx.x * blockDim.x + threadIdx.x;
    if (i >= NPIX) return;
    float s = 0.f;
    #pragma unroll
    for (int r = 0; r < D1; r++)
        s += wsv[i * D1 + r] * buf[os[i * D1 + r] + 1];
    normv[i] = alpha * s + 1e-20f;
}

__global__ void update_q(const float* __restrict__ U, const float* __restrict__ fb,
                         const float* __restrict__ fs, const float* __restrict__ nb,
                         const float* __restrict__ ns, float* __restrict__ Q, int use_msg) {
    int i = blockIdx.x * blockDim.x + threadIdx.x;
    if (i >= NPIX) return;
    float l[NC];
    float mx = -1e30f;
    float inb = 1.f, ins = 1.f;
    if (use_msg) { inb = nb[i]; ins = ns[i]; }
    #pragma unroll
    for (int c = 0; c < NC; c++) {
        float v = -U[i * NC + c];
        if (use_msg)
            v += 10.0f * (fb[i * NC + c] / inb) + 3.0f * (fs[i * NC + c] / ins);
        l[c] = v; mx = fmaxf(mx, v);
    }
    float s = 0.f;
    #pragma unroll
    for (int c = 0; c < NC; c++) { float e = expf(l[c] - mx); l[c] = e; s += e; }
    #pragma unroll
    for (int c = 0; c < NC; c++) Q[i * NC + c] = l[c] / s;
}

// ---------------- host orchestration ----------------
extern "C" void kernel_launch(void* const* d_in, const int* in_sizes, int n_in,
                              void* d_out, int out_size, void* d_ws, size_t ws_size,
                              hipStream_t stream) {
    const float* U     = (const float*)d_in[0];  // (N, 21)
    const float* image = (const float*)d_in[1];  // (N, 3)
    float* Q = (float*)d_out;                    // Q buffer lives in d_out

    char* base = (char*)d_ws;
    size_t off = 0;
    auto alloc = [&](size_t bytes) -> void* {
        off = (off + 255) & ~(size_t)255;
        void* p = base + off; off += bytes; return p;
    };
    int*   os_b = (int*)  alloc((size_t)RB * 4);
    float* ws_b = (float*)alloc((size_t)RB * 4);
    int*   n1_b = (int*)  alloc((size_t)DB1 * RB * 4);
    int*   n2_b = (int*)  alloc((size_t)DB1 * RB * 4);
    unsigned long long* uk_b = (unsigned long long*)alloc((size_t)RB * 8);
    int*   os_s = (int*)  alloc((size_t)RS * 4);
    float* ws_s = (float*)alloc((size_t)RS * 4);
    int*   n1_s = (int*)  alloc((size_t)DS1 * RS * 4);
    int*   n2_s = (int*)  alloc((size_t)DS1 * RS * 4);
    unsigned long long* uk_s = (unsigned long long*)alloc((size_t)RS * 8);
    unsigned long long* hk = (unsigned long long*)alloc((size_t)TBS * 8);
    int*   hid  = (int*)  alloc((size_t)TBS * 4);
    int*   cnt  = (int*)  alloc(256);            // cnt[0]=M_bilateral, cnt[1]=M_spatial
    // inverted index (bilateral)
    int*   cntr_b = (int*)  alloc((size_t)RB * 4);
    int*   off_b  = (int*)  alloc((size_t)RB * 4);
    int*   fill_b = (int*)  alloc((size_t)RB * 4);
    int*   ep_b   = (int*)  alloc((size_t)RB * 4);
    float* ew_b   = (float*)alloc((size_t)RB * 4);
    // inverted index (spatial)
    int*   cntr_s = (int*)  alloc((size_t)RS * 4);
    int*   off_s  = (int*)  alloc((size_t)RS * 4);
    int*   fill_s = (int*)  alloc((size_t)RS * 4);
    int*   ep_s   = (int*)  alloc((size_t)RS * 4);
    float* ew_s   = (float*)alloc((size_t)RS * 4);
    int*   bsums  = (int*)  alloc(64 * 1024);
    float* norm_b = (float*)alloc((size_t)NPIX * 4);
    float* norm_s = (float*)alloc((size_t)NPIX * 4);
    float* fb   = (float*)alloc((size_t)NPIX * NC * 4);
    float* fs   = (float*)alloc((size_t)NPIX * NC * 4);
    float* buf0 = (float*)alloc((size_t)(RB + 1) * NC * 4);
    float* buf1 = (float*)alloc((size_t)(RB + 1) * NC * 4);
    if (off > ws_size) return;  // insufficient scratch -> visible as validation failure

    const float ALPHA_B = (float)(1.0 / (1.0 + exp2(-(double)DB)));  // 32/33
    const float ALPHA_S = (float)(1.0 / (1.0 + exp2(-(double)DS)));  // 4/5

    constexpr int PG = 4096;  // persistent grid blocks for grid-stride kernels

    // ---- build bilateral lattice ----
    hipMemsetAsync(hk, 0xFF, (size_t)TBS * 8, stream);
    hipMemsetAsync(cnt, 0, 8, stream);
    build_bilateral<<<(NPIX + 255) / 256, 256, 0, stream>>>(image, hk, TBS - 1, os_b, ws_b);
    compact_kernel<<<TBS / 256, 256, 0, stream>>>(hk, TBS, hid, uk_b, cnt + 0);
    os_finalize<<<(RB + 255) / 256, 256, 0, stream>>>(os_b, hid, RB);
    build_neighbors<DB><<<(RB + 255) / 256, 256, 0, stream>>>(uk_b, hk, hid, TBS - 1, cnt + 0, RB, n1_b, n2_b);

    // bilateral inverted index
    hipMemsetAsync(cntr_b, 0, (size_t)RB * 4, stream);
    hipMemsetAsync(fill_b, 0, (size_t)RB * 4, stream);
    count_entries<<<(RB + 255) / 256, 256, 0, stream>>>(os_b, cntr_b, RB);
    scan_block<<<RB / 256, 256, 0, stream>>>(cntr_b, off_b, bsums, RB);
    scan_bsums<<<1, 256, 0, stream>>>(bsums, RB / 256);
    finalize_off<<<RB / 256, 256, 0, stream>>>(off_b, cntr_b, bsums, RB);
    fill_entries<<<(RB + 255) / 256, 256, 0, stream>>>(os_b, ws_b, off_b, fill_b, ep_b, ew_b, RB, DB1);

    // ---- build spatial lattice (reuse hash region) ----
    hipMemsetAsync(hk, 0xFF, (size_t)TSS * 8, stream);
    build_spatial<<<(NPIX + 255) / 256, 256, 0, stream>>>(hk, TSS - 1, os_s, ws_s);
    compact_kernel<<<TSS / 256, 256, 0, stream>>>(hk, TSS, hid, uk_s, cnt + 1);
    os_finalize<<<(RS + 255) / 256, 256, 0, stream>>>(os_s, hid, RS);
    build_neighbors<DS><<<(RS + 255) / 256, 256, 0, stream>>>(uk_s, hk, hid, TSS - 1, cnt + 1, RS, n1_s, n2_s);

    // spatial inverted index
    hipMemsetAsync(cntr_s, 0, (size_t)RS * 4, stream);
    hipMemsetAsync(fill_s, 0, (size_t)RS * 4, stream);
    count_entries<<<(RS + 255) / 256, 256, 0, stream>>>(os_s, cntr_s, RS);
    scan_block<<<RS / 256, 256, 0, stream>>>(cntr_s, off_s, bsums, RS);
    scan_bsums<<<1, 256, 0, stream>>>(bsums, RS / 256);
    finalize_off<<<RS / 256, 256, 0, stream>>>(off_s, cntr_s, bsums, RS);
    fill_entries<<<(RS + 255) / 256, 256, 0, stream>>>(os_s, ws_s, off_s, fill_s, ep_s, ew_s, RS, DS1);

    // ---- norm filters (C=1), computed once ----
    {
        gather_splat1<<<1024, 256, 0, stream>>>(off_b, cntr_b, ew_b, buf0, cnt + 0);
        float* a = buf0; float* b = buf1;
        for (int j = 0; j < DB1; j++) {
            blur_step<1><<<1024, 256, 0, stream>>>(a, b, n1_b + (size_t)j * RB, n2_b + (size_t)j * RB, cnt + 0);
            float* t = a; a = b; b = t;
        }
        slice_norm<DB1><<<(NPIX + 255) / 256, 256, 0, stream>>>(a, os_b, ws_b, norm_b, ALPHA_B);

        gather_splat1<<<1024, 256, 0, stream>>>(off_s, cntr_s, ew_s, buf0, cnt + 1);
        a = buf0; b = buf1;
        for (int j = 0; j < DS1; j++) {
            blur_step<1><<<1024, 256, 0, stream>>>(a, b, n1_s + (size_t)j * RS, n2_s + (size_t)j * RS, cnt + 1);
            float* t = a; a = b; b = t;
        }
        slice_norm<DS1><<<(NPIX + 255) / 256, 256, 0, stream>>>(a, os_s, ws_s, norm_s, ALPHA_S);
    }

    // ---- Q0 = softmax(-U) ----
    update_q<<<(NPIX + 255) / 256, 256, 0, stream>>>(U, fb, fs, norm_b, norm_s, Q, 0);

    // ---- 5 mean-field iterations ----
    for (int it = 0; it < 5; it++) {
        // bilateral filter of Q -> fb
        gather_splat<NC><<<PG, 256, 0, stream>>>(Q, off_b, cntr_b, ep_b, ew_b, buf0, cnt + 0);
        float* a = buf0; float* b = buf1;
        for (int j = 0; j < DB1; j++) {
            blur_step<NC><<<PG, 256, 0, stream>>>(a, b, n1_b + (size_t)j * RB, n2_b + (size_t)j * RB, cnt + 0);
            float* t = a; a = b; b = t;
        }
        slice_k<NC, DB1><<<(NPIX * NC + 255) / 256, 256, 0, stream>>>(a, os_b, ws_b, fb, ALPHA_B);

        // spatial filter of Q -> fs
        gather_splat<NC><<<PG, 256, 0, stream>>>(Q, off_s, cntr_s, ep_s, ew_s, buf0, cnt + 1);
        a = buf0; b = buf1;
        for (int j = 0; j < DS1; j++) {
            blur_step<NC><<<PG, 256, 0, stream>>>(a, b, n1_s + (size_t)j * RS, n2_s + (size_t)j * RS, cnt + 1);
            float* t = a; a = b; b = t;
        }
        slice_k<NC, DS1><<<(NPIX * NC + 255) / 256, 256, 0, stream>>>(a, os_s, ws_s, fs, ALPHA_S);

        // Q = softmax(-U + 10*fb/norm_b + 3*fs/norm_s)
        update_q<<<(NPIX + 255) / 256, 256, 0, stream>>>(U, fb, fs, norm_b, norm_s, Q, 1);
    }
}

// Round 3
// 1451.867 us; speedup vs baseline: 5.0690x; 1.1818x over previous
//
#include <hip/hip_runtime.h>
#include <cmath>

// ---------------- problem constants ----------------
constexpr int IMH = 320, IMW = 320, NPIX = IMH * IMW, NC = 21;
constexpr int DB = 5, DB1 = 6;   // bilateral lattice dim
constexpr int DS = 2, DS1 = 3;   // spatial lattice dim
constexpr int RB = NPIX * DB1;   // splat entries (bilateral) = 614400
constexpr int RS = NPIX * DS1;   // (spatial) = 307200
constexpr int TBS = 1 << 20;     // hash table slots (bilateral)
constexpr int TSS = 1 << 18;     // hash table slots (spatial; M_s << 50K by geometry)

#define EMPTY_KEY 0xFFFFFFFFFFFFFFFFULL

__device__ __forceinline__ unsigned long long mix64(unsigned long long x) {
    x ^= x >> 33; x *= 0xff51afd7ed558ccdULL;
    x ^= x >> 33; x *= 0xc4ceb9fe1a85ec53ULL;
    x ^= x >> 33; return x;
}

// ---------------- permutohedral embedding (matches reference op-for-op, f32) ----------------
template<int D>
__device__ void perm_embed(const float* f, float* bary, unsigned long long* pk) {
    constexpr int D1 = D + 1;
    float cf[D];
    #pragma unroll
    for (int i = 0; i < D; i++) {
        double s = sqrt(2.0 / 3.0) * (double)D1 / sqrt((double)((i + 1) * (i + 2)));
        cf[i] = f[i] * (float)s;
    }
    float csum[D];
    float acc = 0.f;
    #pragma unroll
    for (int i = D - 1; i >= 0; i--) { acc += cf[i]; csum[i] = acc; }
    float el[D1];
    el[0] = csum[0];
    #pragma unroll
    for (int i = 1; i < D; i++) el[i] = csum[i] - (float)i * cf[i - 1];
    el[D] = -(float)D * cf[D - 1];
    const float down = 1.0f / (float)D1;
    float rem0[D1]; int rank[D1]; int ssum = 0;
    #pragma unroll
    for (int i = 0; i < D1; i++) {
        float rd = rintf(el[i] * down);
        rem0[i] = rd * (float)D1;
        ssum += (int)rd;
    }
    float diff[D1];
    #pragma unroll
    for (int i = 0; i < D1; i++) diff[i] = el[i] - rem0[i];
    #pragma unroll
    for (int i = 0; i < D1; i++) {
        int r = 0;
        #pragma unroll
        for (int j = 0; j < D1; j++)
            r += (diff[j] > diff[i]) || ((diff[j] == diff[i]) && (j < i));
        rank[i] = r + ssum;
    }
    #pragma unroll
    for (int i = 0; i < D1; i++) {
        if (rank[i] < 0)      { rank[i] += D1; rem0[i] += (float)D1; }
        else if (rank[i] > D) { rank[i] -= D1; rem0[i] -= (float)D1; }
    }
    float b[D + 2];
    #pragma unroll
    for (int i = 0; i < D + 2; i++) b[i] = 0.f;
    #pragma unroll
    for (int i = 0; i < D1; i++) b[D - rank[i]]     += (el[i] - rem0[i]) * down;
    #pragma unroll
    for (int i = 0; i < D1; i++) b[D + 1 - rank[i]] -= (el[i] - rem0[i]) * down;
    b[0] += 1.0f + b[D + 1];
    #pragma unroll
    for (int i = 0; i < D1; i++) bary[i] = b[i];
    int key0[D];
    #pragma unroll
    for (int i = 0; i < D; i++) key0[i] = (int)rintf(rem0[i]);
    #pragma unroll
    for (int r = 0; r < D1; r++) {
        unsigned long long p = 0;
        #pragma unroll
        for (int i = 0; i < D; i++) {
            int c = key0[i] + ((rank[i] < D1 - r) ? r : r - D1);
            p |= ((unsigned long long)((unsigned)(c + 2048) & 0xFFFu)) << (12 * i);
        }
        pk[r] = p;
    }
}

// ---------------- hash table ----------------
__device__ __forceinline__ int hash_insert(unsigned long long* hk, int tmask, unsigned long long k) {
    int slot = (int)(mix64(k) & (unsigned long long)tmask);
    while (true) {
        unsigned long long prev = atomicCAS(&hk[slot], EMPTY_KEY, k);
        if (prev == EMPTY_KEY || prev == k) return slot;
        slot = (slot + 1) & tmask;
    }
}
__device__ __forceinline__ int hash_lookup(const unsigned long long* hk, const int* hid,
                                           int tmask, unsigned long long k) {
    int slot = (int)(mix64(k) & (unsigned long long)tmask);
    while (true) {
        unsigned long long v = hk[slot];
        if (v == k) return hid[slot];
        if (v == EMPTY_KEY) return -1;
        slot = (slot + 1) & tmask;
    }
}

// ---------------- build kernels ----------------
__global__ void build_bilateral(const float* __restrict__ image, unsigned long long* hk,
                                int tmask, int* os, float* wsv) {
    int i = blockIdx.x * blockDim.x + threadIdx.x;
    if (i >= NPIX) return;
    int x = i % IMW, y = i / IMW;
    float f[DB];
    f[0] = (float)x / 80.0f;           // THETA_ALPHA
    f[1] = (float)y / 80.0f;
    f[2] = image[i * 3 + 0] / 13.0f;   // THETA_BETA
    f[3] = image[i * 3 + 1] / 13.0f;
    f[4] = image[i * 3 + 2] / 13.0f;
    float bary[DB1]; unsigned long long pk[DB1];
    perm_embed<DB>(f, bary, pk);
    #pragma unroll
    for (int r = 0; r < DB1; r++) {
        wsv[i * DB1 + r] = bary[r];
        os[i * DB1 + r] = hash_insert(hk, tmask, pk[r]);  // slot; remapped to id later
    }
}

__global__ void build_spatial(unsigned long long* hk, int tmask, int* os, float* wsv) {
    int i = blockIdx.x * blockDim.x + threadIdx.x;
    if (i >= NPIX) return;
    int x = i % IMW, y = i / IMW;
    float f[DS];
    f[0] = (float)x / 3.0f;            // THETA_GAMMA
    f[1] = (float)y / 3.0f;
    float bary[DS1]; unsigned long long pk[DS1];
    perm_embed<DS>(f, bary, pk);
    #pragma unroll
    for (int r = 0; r < DS1; r++) {
        wsv[i * DS1 + r] = bary[r];
        os[i * DS1 + r] = hash_insert(hk, tmask, pk[r]);
    }
}

// ---------------- scan primitives ----------------
// per-256-block inclusive scan of count[]; incl -> incl[], block totals -> bsums
__global__ void scan_block(const int* __restrict__ count, int* incl, int* bsums, int Mcap) {
    __shared__ int sh[256];
    int idx = blockIdx.x * 256 + threadIdx.x;
    int v = (idx < Mcap) ? count[idx] : 0;
    sh[threadIdx.x] = v;
    __syncthreads();
    for (int d = 1; d < 256; d <<= 1) {
        int t = (threadIdx.x >= d) ? sh[threadIdx.x - d] : 0;
        __syncthreads();
        sh[threadIdx.x] += t;
        __syncthreads();
    }
    if (idx < Mcap) incl[idx] = sh[threadIdx.x];
    if (threadIdx.x == 255) bsums[blockIdx.x] = sh[255];
}

// same, but the "count" is hash-table slot occupancy
__global__ void scan_block_occ(const unsigned long long* __restrict__ hk, int* incl,
                               int* bsums, int T) {
    __shared__ int sh[256];
    int idx = blockIdx.x * 256 + threadIdx.x;
    int v = (idx < T && hk[idx] != EMPTY_KEY) ? 1 : 0;
    sh[threadIdx.x] = v;
    __syncthreads();
    for (int d = 1; d < 256; d <<= 1) {
        int t = (threadIdx.x >= d) ? sh[threadIdx.x - d] : 0;
        __syncthreads();
        sh[threadIdx.x] += t;
        __syncthreads();
    }
    if (idx < T) incl[idx] = sh[threadIdx.x];
    if (threadIdx.x == 255) bsums[blockIdx.x] = sh[255];
}

// single-block exclusive scan of block sums (in place); optional grand total out
__global__ void scan_bsums(int* bsums, int nb, int* total_out) {
    __shared__ int sh[256];
    __shared__ int run;
    if (threadIdx.x == 0) run = 0;
    __syncthreads();
    for (int base = 0; base < nb; base += 256) {
        int idx = base + threadIdx.x;
        int v = (idx < nb) ? bsums[idx] : 0;
        sh[threadIdx.x] = v;
        __syncthreads();
        for (int d = 1; d < 256; d <<= 1) {
            int t = (threadIdx.x >= d) ? sh[threadIdx.x - d] : 0;
            __syncthreads();
            sh[threadIdx.x] += t;
            __syncthreads();
        }
        int total = sh[255];
        int excl = sh[threadIdx.x] - v + run;
        if (idx < nb) bsums[idx] = excl;
        __syncthreads();
        if (threadIdx.x == 0) run += total;
        __syncthreads();
    }
    if (total_out != nullptr && threadIdx.x == 0) *total_out = run;
}

// occupied slot s -> id = incl[s]-1 + bsums[s/256]; hid[s]=id; uk[id]=key
__global__ void compact_finalize(const unsigned long long* __restrict__ hk, int* hid,
                                 const int* __restrict__ bsums, unsigned long long* uk, int T) {
    int s = blockIdx.x * 256 + threadIdx.x;
    if (s >= T) return;
    unsigned long long k = hk[s];
    if (k != EMPTY_KEY) {
        int id = hid[s] - 1 + bsums[blockIdx.x];
        hid[s] = id;
        uk[id] = k;
    }
}

// off[idx] = incl[idx] - count[idx] + bsums[idx/256]   (turn incl -> global exclusive)
__global__ void finalize_off(int* off, const int* __restrict__ count,
                             const int* __restrict__ bsums, int Mcap) {
    int idx = blockIdx.x * 256 + threadIdx.x;
    if (idx < Mcap) off[idx] = off[idx] - count[idx] + bsums[blockIdx.x];
}

__global__ void os_finalize(int* os, const int* hid, int R) {
    int i = blockIdx.x * blockDim.x + threadIdx.x;
    if (i < R) os[i] = hid[os[i]];
}

template<int D>
__global__ void build_neighbors(const unsigned long long* uk, const unsigned long long* hk,
                                const int* hid, int tmask, const int* cnt, int stride,
                                int* n1, int* n2) {
    int m = blockIdx.x * blockDim.x + threadIdx.x;
    if (m >= *cnt) return;
    unsigned long long k = uk[m];
    int c[D];
    #pragma unroll
    for (int i = 0; i < D; i++) c[i] = (int)((k >> (12 * i)) & 0xFFFULL) - 2048;
    for (int j = 0; j <= D; j++) {
        unsigned long long p1 = 0, p2 = 0;
        #pragma unroll
        for (int i = 0; i < D; i++) {
            int a = c[i] + ((i == j) ? D : -1);   // key - 1 + (D+1)*e_j
            int b = c[i] + ((i == j) ? -D : 1);   // key + 1 - (D+1)*e_j
            p1 |= ((unsigned long long)((unsigned)(a + 2048) & 0xFFFu)) << (12 * i);
            p2 |= ((unsigned long long)((unsigned)(b + 2048) & 0xFFFu)) << (12 * i);
        }
        n1[j * stride + m] = hash_lookup(hk, hid, tmask, p1);
        n2[j * stride + m] = hash_lookup(hk, hid, tmask, p2);
    }
}

// ---------------- inverted-index build (splat -> gather) ----------------
__global__ void count_entries(const int* __restrict__ os, int* count, int R) {
    int i = blockIdx.x * blockDim.x + threadIdx.x;
    if (i < R) atomicAdd(&count[os[i]], 1);
}

__global__ void fill_entries(const int* __restrict__ os, const float* __restrict__ wsv,
                             const int* __restrict__ off, int* fill,
                             int* ep, float* ew, int R, int D1) {
    int idx = blockIdx.x * blockDim.x + threadIdx.x;
    if (idx >= R) return;
    int m = os[idx];
    int pos = off[m] + atomicAdd(&fill[m], 1);
    ep[pos] = idx / D1;     // pixel index
    ew[pos] = wsv[idx];
}

// ---------------- filter kernels ----------------
// gather splat: buf[0][*]=0 (sink row); buf[m+1][c] = sum_t ew[t]*vals[ep[t]*CC+c]
template<int CC>
__global__ void gather_splat(const float* __restrict__ vals, const int* __restrict__ off,
                             const int* __restrict__ count, const int* __restrict__ ep,
                             const float* __restrict__ ew, float* __restrict__ buf,
                             const int* cnt) {
    int M = *cnt;
    int total = (M + 1) * CC;
    int stride = gridDim.x * blockDim.x;
    for (int idx = blockIdx.x * blockDim.x + threadIdx.x; idx < total; idx += stride) {
        int row = idx / CC, c = idx - row * CC;
        if (row == 0) { buf[idx] = 0.f; continue; }
        int m = row - 1;
        int s = off[m], e = s + count[m];
        float acc = 0.f;
        for (int t = s; t < e; t++)
            acc += ew[t] * vals[(size_t)ep[t] * CC + c];
        buf[idx] = acc;
    }
}

// C=1 norm splat: just the sum of weights per row
__global__ void gather_splat1(const int* __restrict__ off, const int* __restrict__ count,
                              const float* __restrict__ ew, float* __restrict__ buf,
                              const int* cnt) {
    int M = *cnt;
    int stride = gridDim.x * blockDim.x;
    for (int row = blockIdx.x * blockDim.x + threadIdx.x; row <= M; row += stride) {
        if (row == 0) { buf[0] = 0.f; continue; }
        int m = row - 1;
        int s = off[m], e = s + count[m];
        float acc = 0.f;
        for (int t = s; t < e; t++) acc += ew[t];
        buf[row] = acc;
    }
}

template<int CC>
__global__ void blur_step(const float* __restrict__ in, float* __restrict__ out,
                          const int* __restrict__ n1, const int* __restrict__ n2,
                          const int* cnt) {
    int M = *cnt;
    int total = (M + 1) * CC;
    int stride = gridDim.x * blockDim.x;
    for (int idx = blockIdx.x * blockDim.x + threadIdx.x; idx < total; idx += stride) {
        int row = idx / CC, c = idx - row * CC;
        if (row == 0) { out[idx] = 0.f; continue; }  // zero row = missing-neighbor sink
        int m = row - 1;
        float a = in[(n1[m] + 1) * CC + c];
        float b = in[(n2[m] + 1) * CC + c];
        out[idx] = in[idx] + 0.5f * (a + b);
    }
}

template<int CC, int D1>
__global__ void slice_k(const float* __restrict__ buf, const int* __restrict__ os,
                        const float* __restrict__ wsv, float* __restrict__ out, float alpha) {
    int idx = blockIdx.x * blockDim.x + threadIdx.x;
    if (idx >= NPIX * CC) return;
    int i = idx / CC, c = idx - i * CC;
    float s = 0.f;
    #pragma unroll
    for (int r = 0; r < D1; r++)
        s += wsv[i * D1 + r] * buf[(os[i * D1 + r] + 1) * CC + c];
    out[idx] = alpha * s;
}

template<int D1>
__global__ void slice_norm(const float* __restrict__ buf, const int* __restrict__ os,
                           const float* __restrict__ wsv, float* normv, float alpha) {
    int i = blockIdx.x * blockDim.x + threadIdx.x;
    if (i >= NPIX) return;
    float s = 0.f;
    #pragma unroll
    for (int r = 0; r < D1; r++)
        s += wsv[i * D1 + r] * buf[os[i * D1 + r] + 1];
    normv[i] = alpha * s + 1e-20f;
}

__global__ void update_q(const float* __restrict__ U, const float* __restrict__ fb,
                         const float* __restrict__ fs, const float* __restrict__ nb,
                         const float* __restrict__ ns, float* __restrict__ Q, int use_msg) {
    int i = blockIdx.x * blockDim.x + threadIdx.x;
    if (i >= NPIX) return;
    float l[NC];
    float mx = -1e30f;
    float inb = 1.f, ins = 1.f;
    if (use_msg) { inb = nb[i]; ins = ns[i]; }
    #pragma unroll
    for (int c = 0; c < NC; c++) {
        float v = -U[i * NC + c];
        if (use_msg)
            v += 10.0f * (fb[i * NC + c] / inb) + 3.0f * (fs[i * NC + c] / ins);
        l[c] = v; mx = fmaxf(mx, v);
    }
    float s = 0.f;
    #pragma unroll
    for (int c = 0; c < NC; c++) { float e = expf(l[c] - mx); l[c] = e; s += e; }
    #pragma unroll
    for (int c = 0; c < NC; c++) Q[i * NC + c] = l[c] / s;
}

// ---------------- host orchestration ----------------
extern "C" void kernel_launch(void* const* d_in, const int* in_sizes, int n_in,
                              void* d_out, int out_size, void* d_ws, size_t ws_size,
                              hipStream_t stream) {
    const float* U     = (const float*)d_in[0];  // (N, 21)
    const float* image = (const float*)d_in[1];  // (N, 3)
    float* Q = (float*)d_out;                    // Q buffer lives in d_out

    char* base = (char*)d_ws;
    size_t off = 0;
    auto alloc = [&](size_t bytes) -> void* {
        off = (off + 255) & ~(size_t)255;
        void* p = base + off; off += bytes; return p;
    };
    int*   os_b = (int*)  alloc((size_t)RB * 4);
    float* ws_b = (float*)alloc((size_t)RB * 4);
    int*   n1_b = (int*)  alloc((size_t)DB1 * RB * 4);
    int*   n2_b = (int*)  alloc((size_t)DB1 * RB * 4);
    unsigned long long* uk_b = (unsigned long long*)alloc((size_t)RB * 8);
    int*   os_s = (int*)  alloc((size_t)RS * 4);
    float* ws_s = (float*)alloc((size_t)RS * 4);
    int*   n1_s = (int*)  alloc((size_t)DS1 * RS * 4);
    int*   n2_s = (int*)  alloc((size_t)DS1 * RS * 4);
    unsigned long long* uk_s = (unsigned long long*)alloc((size_t)RS * 8);
    unsigned long long* hk = (unsigned long long*)alloc((size_t)TBS * 8);
    int*   hid  = (int*)  alloc((size_t)TBS * 4);
    int*   cnt  = (int*)  alloc(256);            // cnt[0]=M_bilateral, cnt[1]=M_spatial
    // inverted index (bilateral)
    int*   cntr_b = (int*)  alloc((size_t)RB * 4);
    int*   off_b  = (int*)  alloc((size_t)RB * 4);
    int*   fill_b = (int*)  alloc((size_t)RB * 4);
    int*   ep_b   = (int*)  alloc((size_t)RB * 4);
    float* ew_b   = (float*)alloc((size_t)RB * 4);
    // inverted index (spatial)
    int*   cntr_s = (int*)  alloc((size_t)RS * 4);
    int*   off_s  = (int*)  alloc((size_t)RS * 4);
    int*   fill_s = (int*)  alloc((size_t)RS * 4);
    int*   ep_s   = (int*)  alloc((size_t)RS * 4);
    float* ew_s   = (float*)alloc((size_t)RS * 4);
    int*   bsums  = (int*)  alloc(64 * 1024);
    float* norm_b = (float*)alloc((size_t)NPIX * 4);
    float* norm_s = (float*)alloc((size_t)NPIX * 4);
    float* fb   = (float*)alloc((size_t)NPIX * NC * 4);
    float* fs   = (float*)alloc((size_t)NPIX * NC * 4);
    float* buf0 = (float*)alloc((size_t)(RB + 1) * NC * 4);
    float* buf1 = (float*)alloc((size_t)(RB + 1) * NC * 4);
    if (off > ws_size) return;  // insufficient scratch -> visible as validation failure

    const float ALPHA_B = (float)(1.0 / (1.0 + exp2(-(double)DB)));  // 32/33
    const float ALPHA_S = (float)(1.0 / (1.0 + exp2(-(double)DS)));  // 4/5

    constexpr int PG = 4096;  // persistent grid blocks for grid-stride kernels

    // ---- build bilateral lattice ----
    hipMemsetAsync(hk, 0xFF, (size_t)TBS * 8, stream);
    build_bilateral<<<(NPIX + 255) / 256, 256, 0, stream>>>(image, hk, TBS - 1, os_b, ws_b);
    // scan-based compaction (no global atomic serialization)
    scan_block_occ<<<TBS / 256, 256, 0, stream>>>(hk, hid, bsums, TBS);
    scan_bsums<<<1, 256, 0, stream>>>(bsums, TBS / 256, cnt + 0);
    compact_finalize<<<TBS / 256, 256, 0, stream>>>(hk, hid, bsums, uk_b, TBS);
    os_finalize<<<(RB + 255) / 256, 256, 0, stream>>>(os_b, hid, RB);
    build_neighbors<DB><<<(RB + 255) / 256, 256, 0, stream>>>(uk_b, hk, hid, TBS - 1, cnt + 0, RB, n1_b, n2_b);

    // bilateral inverted index
    hipMemsetAsync(cntr_b, 0, (size_t)RB * 4, stream);
    hipMemsetAsync(fill_b, 0, (size_t)RB * 4, stream);
    count_entries<<<(RB + 255) / 256, 256, 0, stream>>>(os_b, cntr_b, RB);
    scan_block<<<RB / 256, 256, 0, stream>>>(cntr_b, off_b, bsums, RB);
    scan_bsums<<<1, 256, 0, stream>>>(bsums, RB / 256, nullptr);
    finalize_off<<<RB / 256, 256, 0, stream>>>(off_b, cntr_b, bsums, RB);
    fill_entries<<<(RB + 255) / 256, 256, 0, stream>>>(os_b, ws_b, off_b, fill_b, ep_b, ew_b, RB, DB1);

    // ---- build spatial lattice (reuse hash region, smaller table) ----
    hipMemsetAsync(hk, 0xFF, (size_t)TSS * 8, stream);
    build_spatial<<<(NPIX + 255) / 256, 256, 0, stream>>>(hk, TSS - 1, os_s, ws_s);
    scan_block_occ<<<TSS / 256, 256, 0, stream>>>(hk, hid, bsums, TSS);
    scan_bsums<<<1, 256, 0, stream>>>(bsums, TSS / 256, cnt + 1);
    compact_finalize<<<TSS / 256, 256, 0, stream>>>(hk, hid, bsums, uk_s, TSS);
    os_finalize<<<(RS + 255) / 256, 256, 0, stream>>>(os_s, hid, RS);
    build_neighbors<DS><<<(RS + 255) / 256, 256, 0, stream>>>(uk_s, hk, hid, TSS - 1, cnt + 1, RS, n1_s, n2_s);

    // spatial inverted index
    hipMemsetAsync(cntr_s, 0, (size_t)RS * 4, stream);
    hipMemsetAsync(fill_s, 0, (size_t)RS * 4, stream);
    count_entries<<<(RS + 255) / 256, 256, 0, stream>>>(os_s, cntr_s, RS);
    scan_block<<<RS / 256, 256, 0, stream>>>(cntr_s, off_s, bsums, RS);
    scan_bsums<<<1, 256, 0, stream>>>(bsums, RS / 256, nullptr);
    finalize_off<<<RS / 256, 256, 0, stream>>>(off_s, cntr_s, bsums, RS);
    fill_entries<<<(RS + 255) / 256, 256, 0, stream>>>(os_s, ws_s, off_s, fill_s, ep_s, ew_s, RS, DS1);

    // ---- norm filters (C=1), computed once ----
    {
        gather_splat1<<<1024, 256, 0, stream>>>(off_b, cntr_b, ew_b, buf0, cnt + 0);
        float* a = buf0; float* b = buf1;
        for (int j = 0; j < DB1; j++) {
            blur_step<1><<<1024, 256, 0, stream>>>(a, b, n1_b + (size_t)j * RB, n2_b + (size_t)j * RB, cnt + 0);
            float* t = a; a = b; b = t;
        }
        slice_norm<DB1><<<(NPIX + 255) / 256, 256, 0, stream>>>(a, os_b, ws_b, norm_b, ALPHA_B);

        gather_splat1<<<1024, 256, 0, stream>>>(off_s, cntr_s, ew_s, buf0, cnt + 1);
        a = buf0; b = buf1;
        for (int j = 0; j < DS1; j++) {
            blur_step<1><<<1024, 256, 0, stream>>>(a, b, n1_s + (size_t)j * RS, n2_s + (size_t)j * RS, cnt + 1);
            float* t = a; a = b; b = t;
        }
        slice_norm<DS1><<<(NPIX + 255) / 256, 256, 0, stream>>>(a, os_s, ws_s, norm_s, ALPHA_S);
    }

    // ---- Q0 = softmax(-U) ----
    update_q<<<(NPIX + 255) / 256, 256, 0, stream>>>(U, fb, fs, norm_b, norm_s, Q, 0);

    // ---- 5 mean-field iterations ----
    for (int it = 0; it < 5; it++) {
        // bilateral filter of Q -> fb
        gather_splat<NC><<<PG, 256, 0, stream>>>(Q, off_b, cntr_b, ep_b, ew_b, buf0, cnt + 0);
        float* a = buf0; float* b = buf1;
        for (int j = 0; j < DB1; j++) {
            blur_step<NC><<<PG, 256, 0, stream>>>(a, b, n1_b + (size_t)j * RB, n2_b + (size_t)j * RB, cnt + 0);
            float* t = a; a = b; b = t;
        }
        slice_k<NC, DB1><<<(NPIX * NC + 255) / 256, 256, 0, stream>>>(a, os_b, ws_b, fb, ALPHA_B);

        // spatial filter of Q -> fs
        gather_splat<NC><<<PG, 256, 0, stream>>>(Q, off_s, cntr_s, ep_s, ew_s, buf0, cnt + 1);
        a = buf0; b = buf1;
        for (int j = 0; j < DS1; j++) {
            blur_step<NC><<<PG, 256, 0, stream>>>(a, b, n1_s + (size_t)j * RS, n2_s + (size_t)j * RS, cnt + 1);
            float* t = a; a = b; b = t;
        }
        slice_k<NC, DS1><<<(NPIX * NC + 255) / 256, 256, 0, stream>>>(a, os_s, ws_s, fs, ALPHA_S);

        // Q = softmax(-U + 10*fb/norm_b + 3*fs/norm_s)
        update_q<<<(NPIX + 255) / 256, 256, 0, stream>>>(U, fb, fs, norm_b, norm_s, Q, 1);
    }
}

// Round 4
// 1365.575 us; speedup vs baseline: 5.3893x; 1.0632x over previous
//
#include <hip/hip_runtime.h>
#include <cmath>

// ---------------- problem constants ----------------
constexpr int IMH = 320, IMW = 320, NPIX = IMH * IMW, NC = 21;
constexpr int CP4 = 6;           // padded channels / 4  (24 floats per row)
constexpr int DB = 5, DB1 = 6;   // bilateral lattice dim
constexpr int DS = 2, DS1 = 3;   // spatial lattice dim
constexpr int RB = NPIX * DB1;   // splat entries (bilateral) = 614400
constexpr int RS = NPIX * DS1;   // (spatial) = 307200
constexpr int TBS = 1 << 20;     // hash table slots (bilateral)
constexpr int TSS = 1 << 18;     // hash table slots (spatial)

#define EMPTY_KEY 0xFFFFFFFFFFFFFFFFULL

__device__ __forceinline__ unsigned long long mix64(unsigned long long x) {
    x ^= x >> 33; x *= 0xff51afd7ed558ccdULL;
    x ^= x >> 33; x *= 0xc4ceb9fe1a85ec53ULL;
    x ^= x >> 33; return x;
}

// ---------------- permutohedral embedding (matches reference op-for-op, f32) ----------------
template<int D>
__device__ void perm_embed(const float* f, float* bary, unsigned long long* pk) {
    constexpr int D1 = D + 1;
    float cf[D];
    #pragma unroll
    for (int i = 0; i < D; i++) {
        double s = sqrt(2.0 / 3.0) * (double)D1 / sqrt((double)((i + 1) * (i + 2)));
        cf[i] = f[i] * (float)s;
    }
    float csum[D];
    float acc = 0.f;
    #pragma unroll
    for (int i = D - 1; i >= 0; i--) { acc += cf[i]; csum[i] = acc; }
    float el[D1];
    el[0] = csum[0];
    #pragma unroll
    for (int i = 1; i < D; i++) el[i] = csum[i] - (float)i * cf[i - 1];
    el[D] = -(float)D * cf[D - 1];
    const float down = 1.0f / (float)D1;
    float rem0[D1]; int rank[D1]; int ssum = 0;
    #pragma unroll
    for (int i = 0; i < D1; i++) {
        float rd = rintf(el[i] * down);
        rem0[i] = rd * (float)D1;
        ssum += (int)rd;
    }
    float diff[D1];
    #pragma unroll
    for (int i = 0; i < D1; i++) diff[i] = el[i] - rem0[i];
    #pragma unroll
    for (int i = 0; i < D1; i++) {
        int r = 0;
        #pragma unroll
        for (int j = 0; j < D1; j++)
            r += (diff[j] > diff[i]) || ((diff[j] == diff[i]) && (j < i));
        rank[i] = r + ssum;
    }
    #pragma unroll
    for (int i = 0; i < D1; i++) {
        if (rank[i] < 0)      { rank[i] += D1; rem0[i] += (float)D1; }
        else if (rank[i] > D) { rank[i] -= D1; rem0[i] -= (float)D1; }
    }
    float b[D + 2];
    #pragma unroll
    for (int i = 0; i < D + 2; i++) b[i] = 0.f;
    #pragma unroll
    for (int i = 0; i < D1; i++) b[D - rank[i]]     += (el[i] - rem0[i]) * down;
    #pragma unroll
    for (int i = 0; i < D1; i++) b[D + 1 - rank[i]] -= (el[i] - rem0[i]) * down;
    b[0] += 1.0f + b[D + 1];
    #pragma unroll
    for (int i = 0; i < D1; i++) bary[i] = b[i];
    int key0[D];
    #pragma unroll
    for (int i = 0; i < D; i++) key0[i] = (int)rintf(rem0[i]);
    #pragma unroll
    for (int r = 0; r < D1; r++) {
        unsigned long long p = 0;
        #pragma unroll
        for (int i = 0; i < D; i++) {
            int c = key0[i] + ((rank[i] < D1 - r) ? r : r - D1);
            p |= ((unsigned long long)((unsigned)(c + 2048) & 0xFFFu)) << (12 * i);
        }
        pk[r] = p;
    }
}

// ---------------- hash table ----------------
__device__ __forceinline__ int hash_insert(unsigned long long* hk, int tmask, unsigned long long k) {
    int slot = (int)(mix64(k) & (unsigned long long)tmask);
    while (true) {
        unsigned long long prev = atomicCAS(&hk[slot], EMPTY_KEY, k);
        if (prev == EMPTY_KEY || prev == k) return slot;
        slot = (slot + 1) & tmask;
    }
}
__device__ __forceinline__ int hash_lookup(const unsigned long long* hk, const int* hid,
                                           int tmask, unsigned long long k) {
    int slot = (int)(mix64(k) & (unsigned long long)tmask);
    while (true) {
        unsigned long long v = hk[slot];
        if (v == k) return hid[slot];
        if (v == EMPTY_KEY) return -1;
        slot = (slot + 1) & tmask;
    }
}

// ---------------- build kernels ----------------
__global__ void build_bilateral(const float* __restrict__ image, unsigned long long* hk,
                                int tmask, int* os, float* wsv) {
    int i = blockIdx.x * blockDim.x + threadIdx.x;
    if (i >= NPIX) return;
    int x = i % IMW, y = i / IMW;
    float f[DB];
    f[0] = (float)x / 80.0f;           // THETA_ALPHA
    f[1] = (float)y / 80.0f;
    f[2] = image[i * 3 + 0] / 13.0f;   // THETA_BETA
    f[3] = image[i * 3 + 1] / 13.0f;
    f[4] = image[i * 3 + 2] / 13.0f;
    float bary[DB1]; unsigned long long pk[DB1];
    perm_embed<DB>(f, bary, pk);
    #pragma unroll
    for (int r = 0; r < DB1; r++) {
        wsv[i * DB1 + r] = bary[r];
        os[i * DB1 + r] = hash_insert(hk, tmask, pk[r]);  // slot; remapped to id later
    }
}

__global__ void build_spatial(unsigned long long* hk, int tmask, int* os, float* wsv) {
    int i = blockIdx.x * blockDim.x + threadIdx.x;
    if (i >= NPIX) return;
    int x = i % IMW, y = i / IMW;
    float f[DS];
    f[0] = (float)x / 3.0f;            // THETA_GAMMA
    f[1] = (float)y / 3.0f;
    float bary[DS1]; unsigned long long pk[DS1];
    perm_embed<DS>(f, bary, pk);
    #pragma unroll
    for (int r = 0; r < DS1; r++) {
        wsv[i * DS1 + r] = bary[r];
        os[i * DS1 + r] = hash_insert(hk, tmask, pk[r]);
    }
}

// ---------------- fused scan kernels (block scan + atomic base; labeling order arbitrary) ----------------
// occupied slot s -> fresh id; hid[s]=id; uk[id]=key; *cnt accumulates M
__global__ void compact_fused(const unsigned long long* __restrict__ hk, int* hid,
                              unsigned long long* uk, int* cnt, int T) {
    __shared__ int sh[256];
    __shared__ int base;
    int idx = blockIdx.x * 256 + threadIdx.x;
    unsigned long long k = (idx < T) ? hk[idx] : EMPTY_KEY;
    int v = (k != EMPTY_KEY) ? 1 : 0;
    sh[threadIdx.x] = v;
    __syncthreads();
    for (int d = 1; d < 256; d <<= 1) {
        int t = (threadIdx.x >= d) ? sh[threadIdx.x - d] : 0;
        __syncthreads();
        sh[threadIdx.x] += t;
        __syncthreads();
    }
    if (threadIdx.x == 255) base = atomicAdd(cnt, sh[255]);
    __syncthreads();
    if (v) {
        int id = base + sh[threadIdx.x] - 1;
        hid[idx] = id;
        uk[id] = k;
    }
}

// exclusive offsets for count[] with arbitrary block ordering; gtot must be zeroed
__global__ void scan_off_fused(const int* __restrict__ count, int* off, int* gtot, int Mcap) {
    __shared__ int sh[256];
    __shared__ int base;
    int idx = blockIdx.x * 256 + threadIdx.x;
    int v = (idx < Mcap) ? count[idx] : 0;
    sh[threadIdx.x] = v;
    __syncthreads();
    for (int d = 1; d < 256; d <<= 1) {
        int t = (threadIdx.x >= d) ? sh[threadIdx.x - d] : 0;
        __syncthreads();
        sh[threadIdx.x] += t;
        __syncthreads();
    }
    if (threadIdx.x == 255) base = atomicAdd(gtot, sh[255]);
    __syncthreads();
    if (idx < Mcap) off[idx] = base + sh[threadIdx.x] - v;
}

// os[i] = id; count[id]++  (fused remap + histogram)
__global__ void os_count_fused(int* os, const int* __restrict__ hid, int* count, int R) {
    int i = blockIdx.x * blockDim.x + threadIdx.x;
    if (i >= R) return;
    int id = hid[os[i]];
    os[i] = id;
    atomicAdd(&count[id], 1);
}

template<int D>
__global__ void build_neighbors(const unsigned long long* uk, const unsigned long long* hk,
                                const int* hid, int tmask, const int* cnt, int stride,
                                int* n1, int* n2) {
    int m = blockIdx.x * blockDim.x + threadIdx.x;
    if (m >= *cnt) return;
    unsigned long long k = uk[m];
    int c[D];
    #pragma unroll
    for (int i = 0; i < D; i++) c[i] = (int)((k >> (12 * i)) & 0xFFFULL) - 2048;
    for (int j = 0; j <= D; j++) {
        unsigned long long p1 = 0, p2 = 0;
        #pragma unroll
        for (int i = 0; i < D; i++) {
            int a = c[i] + ((i == j) ? D : -1);   // key - 1 + (D+1)*e_j
            int b = c[i] + ((i == j) ? -D : 1);   // key + 1 - (D+1)*e_j
            p1 |= ((unsigned long long)((unsigned)(a + 2048) & 0xFFFu)) << (12 * i);
            p2 |= ((unsigned long long)((unsigned)(b + 2048) & 0xFFFu)) << (12 * i);
        }
        n1[j * stride + m] = hash_lookup(hk, hid, tmask, p1);
        n2[j * stride + m] = hash_lookup(hk, hid, tmask, p2);
    }
}

template<int D1>
__global__ void fill_entries(const int* __restrict__ os, const float* __restrict__ wsv,
                             const int* __restrict__ off, int* fill, int2* epw, int R) {
    int idx = blockIdx.x * blockDim.x + threadIdx.x;
    if (idx >= R) return;
    int m = os[idx];
    int pos = off[m] + atomicAdd(&fill[m], 1);
    epw[pos] = make_int2(idx / D1, __float_as_int(wsv[idx]));
}

// ---------------- filter kernels (float4, padded C=24) ----------------
// buf rows: row 0 = zero sink; row m+1 = lattice point m. 6 float4 per row.
__global__ void gather_splat4(const float4* __restrict__ Qp, const int* __restrict__ off,
                              const int* __restrict__ count, const int2* __restrict__ epw,
                              float4* __restrict__ buf, const int* cnt) {
    int M = *cnt;
    int total = (M + 1) * CP4;
    int stride = gridDim.x * blockDim.x;
    for (int idx = blockIdx.x * blockDim.x + threadIdx.x; idx < total; idx += stride) {
        int row = idx / CP4, c4 = idx - row * CP4;
        float4 acc = make_float4(0.f, 0.f, 0.f, 0.f);
        if (row > 0) {
            int m = row - 1;
            int s = off[m], e = s + count[m];
            for (int t = s; t < e; t++) {
                int2 pw = epw[t];
                float w = __int_as_float(pw.y);
                float4 v = Qp[(size_t)pw.x * CP4 + c4];
                acc.x += w * v.x; acc.y += w * v.y; acc.z += w * v.z; acc.w += w * v.w;
            }
        }
        buf[idx] = acc;
    }
}

// C=1 norm splat: just the sum of weights per row
__global__ void gather_splat1(const int* __restrict__ off, const int* __restrict__ count,
                              const int2* __restrict__ epw, float* __restrict__ buf,
                              const int* cnt) {
    int M = *cnt;
    int stride = gridDim.x * blockDim.x;
    for (int row = blockIdx.x * blockDim.x + threadIdx.x; row <= M; row += stride) {
        if (row == 0) { buf[0] = 0.f; continue; }
        int m = row - 1;
        int s = off[m], e = s + count[m];
        float acc = 0.f;
        for (int t = s; t < e; t++) acc += __int_as_float(epw[t].y);
        buf[row] = acc;
    }
}

__global__ void blur4(const float4* __restrict__ in, float4* __restrict__ out,
                      const int* __restrict__ n1, const int* __restrict__ n2,
                      const int* cnt) {
    int M = *cnt;
    int total = (M + 1) * CP4;
    int stride = gridDim.x * blockDim.x;
    for (int idx = blockIdx.x * blockDim.x + threadIdx.x; idx < total; idx += stride) {
        int row = idx / CP4, c4 = idx - row * CP4;
        if (row == 0) { out[idx] = make_float4(0.f, 0.f, 0.f, 0.f); continue; }
        int m = row - 1;
        float4 a = in[(size_t)(n1[m] + 1) * CP4 + c4];
        float4 b = in[(size_t)(n2[m] + 1) * CP4 + c4];
        float4 x = in[idx];
        x.x += 0.5f * (a.x + b.x); x.y += 0.5f * (a.y + b.y);
        x.z += 0.5f * (a.z + b.z); x.w += 0.5f * (a.w + b.w);
        out[idx] = x;
    }
}

__global__ void blur1(const float* __restrict__ in, float* __restrict__ out,
                      const int* __restrict__ n1, const int* __restrict__ n2,
                      const int* cnt) {
    int M = *cnt;
    int stride = gridDim.x * blockDim.x;
    for (int row = blockIdx.x * blockDim.x + threadIdx.x; row <= M; row += stride) {
        if (row == 0) { out[0] = 0.f; continue; }
        int m = row - 1;
        out[row] = in[row] + 0.5f * (in[n1[m] + 1] + in[n2[m] + 1]);
    }
}

template<int D1>
__global__ void slice4(const float4* __restrict__ buf, const int* __restrict__ os,
                       const float* __restrict__ wsv, float4* __restrict__ outp, float alpha) {
    int idx = blockIdx.x * blockDim.x + threadIdx.x;
    if (idx >= NPIX * CP4) return;
    int i = idx / CP4, c4 = idx - i * CP4;
    float4 s = make_float4(0.f, 0.f, 0.f, 0.f);
    #pragma unroll
    for (int r = 0; r < D1; r++) {
        float w = wsv[i * D1 + r];
        float4 v = buf[(size_t)(os[i * D1 + r] + 1) * CP4 + c4];
        s.x += w * v.x; s.y += w * v.y; s.z += w * v.z; s.w += w * v.w;
    }
    s.x *= alpha; s.y *= alpha; s.z *= alpha; s.w *= alpha;
    outp[idx] = s;
}

template<int D1>
__global__ void slice_norm(const float* __restrict__ buf, const int* __restrict__ os,
                           const float* __restrict__ wsv, float* normv, float alpha) {
    int i = blockIdx.x * blockDim.x + threadIdx.x;
    if (i >= NPIX) return;
    float s = 0.f;
    #pragma unroll
    for (int r = 0; r < D1; r++)
        s += wsv[i * D1 + r] * buf[os[i * D1 + r] + 1];
    normv[i] = alpha * s + 1e-20f;
}

// Q (d_out, 21/pixel) + Qp (padded 24/pixel, zero tail) written together
__global__ void update_q(const float* __restrict__ U, const float* __restrict__ fbp,
                         const float* __restrict__ fsp, const float* __restrict__ nb,
                         const float* __restrict__ ns, float* __restrict__ Q,
                         float* __restrict__ Qp, int use_msg) {
    int i = blockIdx.x * blockDim.x + threadIdx.x;
    if (i >= NPIX) return;
    float l[NC];
    float mx = -1e30f;
    float inb = 1.f, ins = 1.f;
    if (use_msg) { inb = nb[i]; ins = ns[i]; }
    #pragma unroll
    for (int c = 0; c < NC; c++) {
        float v = -U[i * NC + c];
        if (use_msg)
            v += 10.0f * (fbp[i * 24 + c] / inb) + 3.0f * (fsp[i * 24 + c] / ins);
        l[c] = v; mx = fmaxf(mx, v);
    }
    float s = 0.f;
    #pragma unroll
    for (int c = 0; c < NC; c++) { float e = expf(l[c] - mx); l[c] = e; s += e; }
    float inv = 1.0f / s;
    #pragma unroll
    for (int c = 0; c < NC; c++) {
        float q = l[c] * inv;
        Q[i * NC + c] = q;
        Qp[i * 24 + c] = q;
    }
    Qp[i * 24 + 21] = 0.f; Qp[i * 24 + 22] = 0.f; Qp[i * 24 + 23] = 0.f;
}

// ---------------- host orchestration ----------------
extern "C" void kernel_launch(void* const* d_in, const int* in_sizes, int n_in,
                              void* d_out, int out_size, void* d_ws, size_t ws_size,
                              hipStream_t stream) {
    const float* U     = (const float*)d_in[0];  // (N, 21)
    const float* image = (const float*)d_in[1];  // (N, 3)
    float* Q = (float*)d_out;                    // exact output (N,21)

    char* base = (char*)d_ws;
    size_t off = 0;
    auto alloc = [&](size_t bytes) -> void* {
        off = (off + 255) & ~(size_t)255;
        void* p = base + off; off += bytes; return p;
    };
    int*   os_b = (int*)  alloc((size_t)RB * 4);
    float* ws_b = (float*)alloc((size_t)RB * 4);
    int*   n1_b = (int*)  alloc((size_t)DB1 * RB * 4);
    int*   n2_b = (int*)  alloc((size_t)DB1 * RB * 4);
    unsigned long long* uk_b = (unsigned long long*)alloc((size_t)RB * 8);
    int*   os_s = (int*)  alloc((size_t)RS * 4);
    float* ws_s = (float*)alloc((size_t)RS * 4);
    int*   n1_s = (int*)  alloc((size_t)DS1 * RS * 4);
    int*   n2_s = (int*)  alloc((size_t)DS1 * RS * 4);
    unsigned long long* uk_s = (unsigned long long*)alloc((size_t)RS * 8);
    unsigned long long* hk = (unsigned long long*)alloc((size_t)TBS * 8);
    int*   hid  = (int*)  alloc((size_t)TBS * 4);
    int*   cnt  = (int*)  alloc(256);   // [0]=M_b, [1]=M_s, [2]=gtot_b, [3]=gtot_s
    // inverted index (bilateral)
    int*   cntr_b = (int*)  alloc((size_t)RB * 4);
    int*   off_b  = (int*)  alloc((size_t)RB * 4);
    int*   fill_b = (int*)  alloc((size_t)RB * 4);
    int2*  epw_b  = (int2*) alloc((size_t)RB * 8);
    // inverted index (spatial)
    int*   cntr_s = (int*)  alloc((size_t)RS * 4);
    int*   off_s  = (int*)  alloc((size_t)RS * 4);
    int*   fill_s = (int*)  alloc((size_t)RS * 4);
    int2*  epw_s  = (int2*) alloc((size_t)RS * 8);
    float* norm_b = (float*)alloc((size_t)NPIX * 4);
    float* norm_s = (float*)alloc((size_t)NPIX * 4);
    float4* Qp  = (float4*)alloc((size_t)NPIX * CP4 * 16);
    float4* fbp = (float4*)alloc((size_t)NPIX * CP4 * 16);
    float4* fsp = (float4*)alloc((size_t)NPIX * CP4 * 16);
    float4* buf0 = (float4*)alloc((size_t)(RB + 1) * CP4 * 16);
    float4* buf1 = (float4*)alloc((size_t)(RB + 1) * CP4 * 16);
    if (off > ws_size) return;  // insufficient scratch -> visible as validation failure

    const float ALPHA_B = (float)(1.0 / (1.0 + exp2(-(double)DB)));  // 32/33
    const float ALPHA_S = (float)(1.0 / (1.0 + exp2(-(double)DS)));  // 4/5

    constexpr int PG = 4096;  // persistent grid blocks for grid-stride kernels

    hipMemsetAsync(cnt, 0, 16, stream);

    // ---- build bilateral lattice ----
    hipMemsetAsync(hk, 0xFF, (size_t)TBS * 8, stream);
    hipMemsetAsync(cntr_b, 0, (size_t)RB * 4, stream);
    hipMemsetAsync(fill_b, 0, (size_t)RB * 4, stream);
    build_bilateral<<<(NPIX + 255) / 256, 256, 0, stream>>>(image, hk, TBS - 1, os_b, ws_b);
    compact_fused<<<TBS / 256, 256, 0, stream>>>(hk, hid, uk_b, cnt + 0, TBS);
    os_count_fused<<<(RB + 255) / 256, 256, 0, stream>>>(os_b, hid, cntr_b, RB);
    build_neighbors<DB><<<(RB + 255) / 256, 256, 0, stream>>>(uk_b, hk, hid, TBS - 1, cnt + 0, RB, n1_b, n2_b);
    scan_off_fused<<<RB / 256, 256, 0, stream>>>(cntr_b, off_b, cnt + 2, RB);
    fill_entries<DB1><<<(RB + 255) / 256, 256, 0, stream>>>(os_b, ws_b, off_b, fill_b, epw_b, RB);

    // ---- build spatial lattice (reuse hash region, smaller table) ----
    hipMemsetAsync(hk, 0xFF, (size_t)TSS * 8, stream);
    hipMemsetAsync(cntr_s, 0, (size_t)RS * 4, stream);
    hipMemsetAsync(fill_s, 0, (size_t)RS * 4, stream);
    build_spatial<<<(NPIX + 255) / 256, 256, 0, stream>>>(hk, TSS - 1, os_s, ws_s);
    compact_fused<<<TSS / 256, 256, 0, stream>>>(hk, hid, uk_s, cnt + 1, TSS);
    os_count_fused<<<(RS + 255) / 256, 256, 0, stream>>>(os_s, hid, cntr_s, RS);
    build_neighbors<DS><<<(RS + 255) / 256, 256, 0, stream>>>(uk_s, hk, hid, TSS - 1, cnt + 1, RS, n1_s, n2_s);
    scan_off_fused<<<RS / 256, 256, 0, stream>>>(cntr_s, off_s, cnt + 3, RS);
    fill_entries<DS1><<<(RS + 255) / 256, 256, 0, stream>>>(os_s, ws_s, off_s, fill_s, epw_s, RS);

    // ---- norm filters (C=1), computed once ----
    {
        float* nb0 = (float*)buf0; float* nb1 = (float*)buf1;
        gather_splat1<<<1024, 256, 0, stream>>>(off_b, cntr_b, epw_b, nb0, cnt + 0);
        float* a = nb0; float* b = nb1;
        for (int j = 0; j < DB1; j++) {
            blur1<<<1024, 256, 0, stream>>>(a, b, n1_b + (size_t)j * RB, n2_b + (size_t)j * RB, cnt + 0);
            float* t = a; a = b; b = t;
        }
        slice_norm<DB1><<<(NPIX + 255) / 256, 256, 0, stream>>>(a, os_b, ws_b, norm_b, ALPHA_B);

        gather_splat1<<<1024, 256, 0, stream>>>(off_s, cntr_s, epw_s, nb0, cnt + 1);
        a = nb0; b = nb1;
        for (int j = 0; j < DS1; j++) {
            blur1<<<1024, 256, 0, stream>>>(a, b, n1_s + (size_t)j * RS, n2_s + (size_t)j * RS, cnt + 1);
            float* t = a; a = b; b = t;
        }
        slice_norm<DS1><<<(NPIX + 255) / 256, 256, 0, stream>>>(a, os_s, ws_s, norm_s, ALPHA_S);
    }

    // ---- Q0 = softmax(-U) ----
    update_q<<<(NPIX + 255) / 256, 256, 0, stream>>>(U, (const float*)fbp, (const float*)fsp,
                                                     norm_b, norm_s, Q, (float*)Qp, 0);

    // ---- 5 mean-field iterations ----
    for (int it = 0; it < 5; it++) {
        // bilateral filter of Qp -> fbp
        gather_splat4<<<PG, 256, 0, stream>>>(Qp, off_b, cntr_b, epw_b, buf0, cnt + 0);
        float4* a = buf0; float4* b = buf1;
        for (int j = 0; j < DB1; j++) {
            blur4<<<PG, 256, 0, stream>>>(a, b, n1_b + (size_t)j * RB, n2_b + (size_t)j * RB, cnt + 0);
            float4* t = a; a = b; b = t;
        }
        slice4<DB1><<<(NPIX * CP4 + 255) / 256, 256, 0, stream>>>(a, os_b, ws_b, fbp, ALPHA_B);

        // spatial filter of Qp -> fsp
        gather_splat4<<<PG, 256, 0, stream>>>(Qp, off_s, cntr_s, epw_s, buf0, cnt + 1);
        a = buf0; b = buf1;
        for (int j = 0; j < DS1; j++) {
            blur4<<<PG, 256, 0, stream>>>(a, b, n1_s + (size_t)j * RS, n2_s + (size_t)j * RS, cnt + 1);
            float4* t = a; a = b; b = t;
        }
        slice4<DS1><<<(NPIX * CP4 + 255) / 256, 256, 0, stream>>>(a, os_s, ws_s, fsp, ALPHA_S);

        // Q = softmax(-U + 10*fb/norm_b + 3*fs/norm_s)
        update_q<<<(NPIX + 255) / 256, 256, 0, stream>>>(U, (const float*)fbp, (const float*)fsp,
                                                         norm_b, norm_s, Q, (float*)Qp, 1);
    }
}

// Round 5
// 1287.902 us; speedup vs baseline: 5.7144x; 1.0603x over previous
//
#include <hip/hip_runtime.h>
#include <cmath>

// ---------------- problem constants ----------------
constexpr int IMH = 320, IMW = 320, NPIX = IMH * IMW, NC = 21;
constexpr int CP4 = 6;           // padded channels / 4  (24 floats per row)
constexpr int DB = 5, DB1 = 6;   // bilateral lattice dim
constexpr int DS = 2, DS1 = 3;   // spatial lattice dim
constexpr int RB = NPIX * DB1;   // splat entries (bilateral) = 614400
constexpr int RS = NPIX * DS1;   // (spatial) = 307200
constexpr int TBS = 1 << 20;     // hash table slots (bilateral)
constexpr int TSS = 1 << 18;     // hash table slots (spatial)
constexpr int NBUCK = 1 << 16;   // spatial-sort buckets (c0,c1 low bytes)

#define EMPTY_KEY 0xFFFFFFFFFFFFFFFFULL

__device__ __forceinline__ unsigned long long mix64(unsigned long long x) {
    x ^= x >> 33; x *= 0xff51afd7ed558ccdULL;
    x ^= x >> 33; x *= 0xc4ceb9fe1a85ec53ULL;
    x ^= x >> 33; return x;
}

// ---------------- permutohedral embedding (matches reference op-for-op, f32) ----------------
template<int D>
__device__ void perm_embed(const float* f, float* bary, unsigned long long* pk) {
    constexpr int D1 = D + 1;
    float cf[D];
    #pragma unroll
    for (int i = 0; i < D; i++) {
        double s = sqrt(2.0 / 3.0) * (double)D1 / sqrt((double)((i + 1) * (i + 2)));
        cf[i] = f[i] * (float)s;
    }
    float csum[D];
    float acc = 0.f;
    #pragma unroll
    for (int i = D - 1; i >= 0; i--) { acc += cf[i]; csum[i] = acc; }
    float el[D1];
    el[0] = csum[0];
    #pragma unroll
    for (int i = 1; i < D; i++) el[i] = csum[i] - (float)i * cf[i - 1];
    el[D] = -(float)D * cf[D - 1];
    const float down = 1.0f / (float)D1;
    float rem0[D1]; int rank[D1]; int ssum = 0;
    #pragma unroll
    for (int i = 0; i < D1; i++) {
        float rd = rintf(el[i] * down);
        rem0[i] = rd * (float)D1;
        ssum += (int)rd;
    }
    float diff[D1];
    #pragma unroll
    for (int i = 0; i < D1; i++) diff[i] = el[i] - rem0[i];
    #pragma unroll
    for (int i = 0; i < D1; i++) {
        int r = 0;
        #pragma unroll
        for (int j = 0; j < D1; j++)
            r += (diff[j] > diff[i]) || ((diff[j] == diff[i]) && (j < i));
        rank[i] = r + ssum;
    }
    #pragma unroll
    for (int i = 0; i < D1; i++) {
        if (rank[i] < 0)      { rank[i] += D1; rem0[i] += (float)D1; }
        else if (rank[i] > D) { rank[i] -= D1; rem0[i] -= (float)D1; }
    }
    float b[D + 2];
    #pragma unroll
    for (int i = 0; i < D + 2; i++) b[i] = 0.f;
    #pragma unroll
    for (int i = 0; i < D1; i++) b[D - rank[i]]     += (el[i] - rem0[i]) * down;
    #pragma unroll
    for (int i = 0; i < D1; i++) b[D + 1 - rank[i]] -= (el[i] - rem0[i]) * down;
    b[0] += 1.0f + b[D + 1];
    #pragma unroll
    for (int i = 0; i < D1; i++) bary[i] = b[i];
    int key0[D];
    #pragma unroll
    for (int i = 0; i < D; i++) key0[i] = (int)rintf(rem0[i]);
    #pragma unroll
    for (int r = 0; r < D1; r++) {
        unsigned long long p = 0;
        #pragma unroll
        for (int i = 0; i < D; i++) {
            int c = key0[i] + ((rank[i] < D1 - r) ? r : r - D1);
            p |= ((unsigned long long)((unsigned)(c + 2048) & 0xFFFu)) << (12 * i);
        }
        pk[r] = p;
    }
}

// ---------------- hash table ----------------
__device__ __forceinline__ int hash_insert(unsigned long long* hk, int tmask, unsigned long long k) {
    int slot = (int)(mix64(k) & (unsigned long long)tmask);
    while (true) {
        unsigned long long prev = atomicCAS(&hk[slot], EMPTY_KEY, k);
        if (prev == EMPTY_KEY || prev == k) return slot;
        slot = (slot + 1) & tmask;
    }
}
__device__ __forceinline__ int hash_lookup(const unsigned long long* hk, const int* hid,
                                           int tmask, unsigned long long k) {
    int slot = (int)(mix64(k) & (unsigned long long)tmask);
    while (true) {
        unsigned long long v = hk[slot];
        if (v == k) return hid[slot];
        if (v == EMPTY_KEY) return -1;
        slot = (slot + 1) & tmask;
    }
}

// bucket code from low bytes of first two (biased) lattice coords; +2048 bias
// vanishes mod 256, so adjacent coords -> adjacent buckets.
__device__ __forceinline__ int key_code(unsigned long long k) {
    int c0 = (int)(k & 0xFFFULL);
    int c1 = (int)((k >> 12) & 0xFFFULL);
    return ((c0 & 0xFF) << 8) | (c1 & 0xFF);
}

// ---------------- build kernels ----------------
__global__ void build_bilateral(const float* __restrict__ image, unsigned long long* hk,
                                int tmask, int* os, float* wsv) {
    int i = blockIdx.x * blockDim.x + threadIdx.x;
    if (i >= NPIX) return;
    int x = i % IMW, y = i / IMW;
    float f[DB];
    f[0] = (float)x / 80.0f;           // THETA_ALPHA
    f[1] = (float)y / 80.0f;
    f[2] = image[i * 3 + 0] / 13.0f;   // THETA_BETA
    f[3] = image[i * 3 + 1] / 13.0f;
    f[4] = image[i * 3 + 2] / 13.0f;
    float bary[DB1]; unsigned long long pk[DB1];
    perm_embed<DB>(f, bary, pk);
    #pragma unroll
    for (int r = 0; r < DB1; r++) {
        wsv[i * DB1 + r] = bary[r];
        os[i * DB1 + r] = hash_insert(hk, tmask, pk[r]);  // slot; remapped to id later
    }
}

__global__ void build_spatial(unsigned long long* hk, int tmask, int* os, float* wsv) {
    int i = blockIdx.x * blockDim.x + threadIdx.x;
    if (i >= NPIX) return;
    int x = i % IMW, y = i / IMW;
    float f[DS];
    f[0] = (float)x / 3.0f;            // THETA_GAMMA
    f[1] = (float)y / 3.0f;
    float bary[DS1]; unsigned long long pk[DS1];
    perm_embed<DS>(f, bary, pk);
    #pragma unroll
    for (int r = 0; r < DS1; r++) {
        wsv[i * DS1 + r] = bary[r];
        os[i * DS1 + r] = hash_insert(hk, tmask, pk[r]);
    }
}

// ---------------- barrier-free scan machinery ----------------
// wave-inclusive scan of count[]; incl -> incl[], per-wave totals -> wsum[]
__global__ void scan_wave_partial(const int* __restrict__ count, int* incl, int* wsum, int n) {
    int idx = blockIdx.x * blockDim.x + threadIdx.x;
    int lane = threadIdx.x & 63;
    int v = (idx < n) ? count[idx] : 0;
    int s = v;
    #pragma unroll
    for (int d = 1; d < 64; d <<= 1) {
        int t = __shfl_up(s, d);
        if (lane >= d) s += t;
    }
    if (idx < n) incl[idx] = s;
    if (lane == 63) wsum[idx >> 6] = s;
}

// single-block in-place exclusive scan of wave totals (nw small); grand total -> total_out
__global__ void scan_partials_excl(int* w, int nw, int* total_out) {
    __shared__ int sh[256];
    __shared__ int run;
    if (threadIdx.x == 0) run = 0;
    __syncthreads();
    for (int basei = 0; basei < nw; basei += 256) {
        int idx = basei + threadIdx.x;
        int v = (idx < nw) ? w[idx] : 0;
        sh[threadIdx.x] = v;
        __syncthreads();
        for (int d = 1; d < 256; d <<= 1) {
            int t = (threadIdx.x >= d) ? sh[threadIdx.x - d] : 0;
            __syncthreads();
            sh[threadIdx.x] += t;
            __syncthreads();
        }
        int total = sh[255];
        if (idx < nw) w[idx] = run + sh[threadIdx.x] - v;
        __syncthreads();
        if (threadIdx.x == 0) run += total;
        __syncthreads();
    }
    if (total_out != nullptr && threadIdx.x == 0) *total_out = run;
}

// off[i] = incl[i] - count[i] + wsumExcl[i/64]   (globally ordered exclusive offsets)
__global__ void scan_finalize(int* off, const int* __restrict__ count,
                              const int* __restrict__ wsum, int n) {
    int idx = blockIdx.x * blockDim.x + threadIdx.x;
    if (idx < n) off[idx] = off[idx] - count[idx] + wsum[idx >> 6];
}

// ---------------- bucket-sorted compaction (two barrier-free slot passes) ----------------
__global__ void hist_keys(const unsigned long long* __restrict__ hk, int* hist, int T) {
    int s = blockIdx.x * blockDim.x + threadIdx.x;
    if (s >= T) return;
    unsigned long long k = hk[s];
    if (k != EMPTY_KEY) atomicAdd(&hist[key_code(k)], 1);
}

__global__ void assign_ids(const unsigned long long* __restrict__ hk, int* hid,
                           const int* __restrict__ histOff, int* histFill,
                           unsigned long long* uk, int T) {
    int s = blockIdx.x * blockDim.x + threadIdx.x;
    if (s >= T) return;
    unsigned long long k = hk[s];
    if (k == EMPTY_KEY) return;
    int code = key_code(k);
    int id = histOff[code] + atomicAdd(&histFill[code], 1);
    hid[s] = id;
    uk[id] = k;
}

// os[i] = id; count[id]++  (fused remap + histogram)
__global__ void os_count_fused(int* os, const int* __restrict__ hid, int* count, int R) {
    int i = blockIdx.x * blockDim.x + threadIdx.x;
    if (i >= R) return;
    int id = hid[os[i]];
    os[i] = id;
    atomicAdd(&count[id], 1);
}

template<int D>
__global__ void build_neighbors(const unsigned long long* uk, const unsigned long long* hk,
                                const int* hid, int tmask, const int* cnt, int stride,
                                int* n1, int* n2) {
    int m = blockIdx.x * blockDim.x + threadIdx.x;
    if (m >= *cnt) return;
    unsigned long long k = uk[m];
    int c[D];
    #pragma unroll
    for (int i = 0; i < D; i++) c[i] = (int)((k >> (12 * i)) & 0xFFFULL) - 2048;
    for (int j = 0; j <= D; j++) {
        unsigned long long p1 = 0, p2 = 0;
        #pragma unroll
        for (int i = 0; i < D; i++) {
            int a = c[i] + ((i == j) ? D : -1);   // key - 1 + (D+1)*e_j
            int b = c[i] + ((i == j) ? -D : 1);   // key + 1 - (D+1)*e_j
            p1 |= ((unsigned long long)((unsigned)(a + 2048) & 0xFFFu)) << (12 * i);
            p2 |= ((unsigned long long)((unsigned)(b + 2048) & 0xFFFu)) << (12 * i);
        }
        n1[j * stride + m] = hash_lookup(hk, hid, tmask, p1);
        n2[j * stride + m] = hash_lookup(hk, hid, tmask, p2);
    }
}

template<int D1>
__global__ void fill_entries(const int* __restrict__ os, const float* __restrict__ wsv,
                             const int* __restrict__ off, int* fill, int2* epw, int R) {
    int idx = blockIdx.x * blockDim.x + threadIdx.x;
    if (idx >= R) return;
    int m = os[idx];
    int pos = off[m] + atomicAdd(&fill[m], 1);
    epw[pos] = make_int2(idx / D1, __float_as_int(wsv[idx]));
}

// ---------------- filter kernels (float4, padded C=24) ----------------
// buf rows: row 0 = zero sink; row m+1 = lattice point m. 6 float4 per row.
__global__ void gather_splat4(const float4* __restrict__ Qp, const int* __restrict__ off,
                              const int* __restrict__ count, const int2* __restrict__ epw,
                              float4* __restrict__ buf, const int* cnt) {
    int M = *cnt;
    int total = (M + 1) * CP4;
    int stride = gridDim.x * blockDim.x;
    for (int idx = blockIdx.x * blockDim.x + threadIdx.x; idx < total; idx += stride) {
        int row = idx / CP4, c4 = idx - row * CP4;
        float4 acc = make_float4(0.f, 0.f, 0.f, 0.f);
        if (row > 0) {
            int m = row - 1;
            int s = off[m], e = s + count[m];
            for (int t = s; t < e; t++) {
                int2 pw = epw[t];
                float w = __int_as_float(pw.y);
                float4 v = Qp[(size_t)pw.x * CP4 + c4];
                acc.x += w * v.x; acc.y += w * v.y; acc.z += w * v.z; acc.w += w * v.w;
            }
        }
        buf[idx] = acc;
    }
}

// C=1 norm splat: just the sum of weights per row
__global__ void gather_splat1(const int* __restrict__ off, const int* __restrict__ count,
                              const int2* __restrict__ epw, float* __restrict__ buf,
                              const int* cnt) {
    int M = *cnt;
    int stride = gridDim.x * blockDim.x;
    for (int row = blockIdx.x * blockDim.x + threadIdx.x; row <= M; row += stride) {
        if (row == 0) { buf[0] = 0.f; continue; }
        int m = row - 1;
        int s = off[m], e = s + count[m];
        float acc = 0.f;
        for (int t = s; t < e; t++) acc += __int_as_float(epw[t].y);
        buf[row] = acc;
    }
}

__global__ void blur4(const float4* __restrict__ in, float4* __restrict__ out,
                      const int* __restrict__ n1, const int* __restrict__ n2,
                      const int* cnt) {
    int M = *cnt;
    int total = (M + 1) * CP4;
    int stride = gridDim.x * blockDim.x;
    for (int idx = blockIdx.x * blockDim.x + threadIdx.x; idx < total; idx += stride) {
        int row = idx / CP4, c4 = idx - row * CP4;
        if (row == 0) { out[idx] = make_float4(0.f, 0.f, 0.f, 0.f); continue; }
        int m = row - 1;
        float4 a = in[(size_t)(n1[m] + 1) * CP4 + c4];
        float4 b = in[(size_t)(n2[m] + 1) * CP4 + c4];
        float4 x = in[idx];
        x.x += 0.5f * (a.x + b.x); x.y += 0.5f * (a.y + b.y);
        x.z += 0.5f * (a.z + b.z); x.w += 0.5f * (a.w + b.w);
        out[idx] = x;
    }
}

__global__ void blur1(const float* __restrict__ in, float* __restrict__ out,
                      const int* __restrict__ n1, const int* __restrict__ n2,
                      const int* cnt) {
    int M = *cnt;
    int stride = gridDim.x * blockDim.x;
    for (int row = blockIdx.x * blockDim.x + threadIdx.x; row <= M; row += stride) {
        if (row == 0) { out[0] = 0.f; continue; }
        int m = row - 1;
        out[row] = in[row] + 0.5f * (in[n1[m] + 1] + in[n2[m] + 1]);
    }
}

template<int D1>
__global__ void slice4(const float4* __restrict__ buf, const int* __restrict__ os,
                       const float* __restrict__ wsv, float4* __restrict__ outp, float alpha) {
    int idx = blockIdx.x * blockDim.x + threadIdx.x;
    if (idx >= NPIX * CP4) return;
    int i = idx / CP4, c4 = idx - i * CP4;
    float4 s = make_float4(0.f, 0.f, 0.f, 0.f);
    #pragma unroll
    for (int r = 0; r < D1; r++) {
        float w = wsv[i * D1 + r];
        float4 v = buf[(size_t)(os[i * D1 + r] + 1) * CP4 + c4];
        s.x += w * v.x; s.y += w * v.y; s.z += w * v.z; s.w += w * v.w;
    }
    s.x *= alpha; s.y *= alpha; s.z *= alpha; s.w *= alpha;
    outp[idx] = s;
}

template<int D1>
__global__ void slice_norm(const float* __restrict__ buf, const int* __restrict__ os,
                           const float* __restrict__ wsv, float* normv, float alpha) {
    int i = blockIdx.x * blockDim.x + threadIdx.x;
    if (i >= NPIX) return;
    float s = 0.f;
    #pragma unroll
    for (int r = 0; r < D1; r++)
        s += wsv[i * D1 + r] * buf[os[i * D1 + r] + 1];
    normv[i] = alpha * s + 1e-20f;
}

// Q (d_out, 21/pixel) + Qp (padded 24/pixel, zero tail) written together
__global__ void update_q(const float* __restrict__ U, const float4* __restrict__ fbp,
                         const float4* __restrict__ fsp, const float* __restrict__ nb,
                         const float* __restrict__ ns, float* __restrict__ Q,
                         float4* __restrict__ Qp, int use_msg) {
    int i = blockIdx.x * blockDim.x + threadIdx.x;
    if (i >= NPIX) return;
    float msg[24];
    if (use_msg) {
        float inb = 10.0f / nb[i], ins = 3.0f / ns[i];
        #pragma unroll
        for (int t = 0; t < CP4; t++) {
            float4 a = fbp[i * CP4 + t];
            float4 b = fsp[i * CP4 + t];
            msg[4 * t + 0] = inb * a.x + ins * b.x;
            msg[4 * t + 1] = inb * a.y + ins * b.y;
            msg[4 * t + 2] = inb * a.z + ins * b.z;
            msg[4 * t + 3] = inb * a.w + ins * b.w;
        }
    } else {
        #pragma unroll
        for (int t = 0; t < 24; t++) msg[t] = 0.f;
    }
    float l[NC];
    float mx = -1e30f;
    #pragma unroll
    for (int c = 0; c < NC; c++) {
        float v = -U[i * NC + c] + msg[c];
        l[c] = v; mx = fmaxf(mx, v);
    }
    float s = 0.f;
    #pragma unroll
    for (int c = 0; c < NC; c++) { float e = expf(l[c] - mx); l[c] = e; s += e; }
    float inv = 1.0f / s;
    float q[24];
    #pragma unroll
    for (int c = 0; c < NC; c++) {
        q[c] = l[c] * inv;
        Q[i * NC + c] = q[c];
    }
    q[21] = 0.f; q[22] = 0.f; q[23] = 0.f;
    #pragma unroll
    for (int t = 0; t < CP4; t++)
        Qp[i * CP4 + t] = make_float4(q[4 * t], q[4 * t + 1], q[4 * t + 2], q[4 * t + 3]);
}

// ---------------- host orchestration ----------------
extern "C" void kernel_launch(void* const* d_in, const int* in_sizes, int n_in,
                              void* d_out, int out_size, void* d_ws, size_t ws_size,
                              hipStream_t stream) {
    const float* U     = (const float*)d_in[0];  // (N, 21)
    const float* image = (const float*)d_in[1];  // (N, 3)
    float* Q = (float*)d_out;                    // exact output (N,21)

    char* base = (char*)d_ws;
    size_t off = 0;
    auto alloc = [&](size_t bytes) -> void* {
        off = (off + 255) & ~(size_t)255;
        void* p = base + off; off += bytes; return p;
    };
    int*   os_b = (int*)  alloc((size_t)RB * 4);
    float* ws_b = (float*)alloc((size_t)RB * 4);
    int*   n1_b = (int*)  alloc((size_t)DB1 * RB * 4);
    int*   n2_b = (int*)  alloc((size_t)DB1 * RB * 4);
    unsigned long long* uk_b = (unsigned long long*)alloc((size_t)RB * 8);
    int*   os_s = (int*)  alloc((size_t)RS * 4);
    float* ws_s = (float*)alloc((size_t)RS * 4);
    int*   n1_s = (int*)  alloc((size_t)DS1 * RS * 4);
    int*   n2_s = (int*)  alloc((size_t)DS1 * RS * 4);
    unsigned long long* uk_s = (unsigned long long*)alloc((size_t)RS * 8);
    unsigned long long* hk = (unsigned long long*)alloc((size_t)TBS * 8);
    int*   hid  = (int*)  alloc((size_t)TBS * 4);
    int*   cnt  = (int*)  alloc(256);   // [0]=M_b, [1]=M_s, [2]=gtot_b, [3]=gtot_s
    // bucket-sort scratch
    int*   hist     = (int*)alloc((size_t)NBUCK * 4);
    int*   histOff  = (int*)alloc((size_t)NBUCK * 4);
    int*   histFill = (int*)alloc((size_t)NBUCK * 4);
    int*   wsums    = (int*)alloc((size_t)(RB / 64) * 4);   // >= max wave count needed
    // inverted index (bilateral)
    int*   cntr_b = (int*)  alloc((size_t)RB * 4);
    int*   off_b  = (int*)  alloc((size_t)RB * 4);
    int*   fill_b = (int*)  alloc((size_t)RB * 4);
    int2*  epw_b  = (int2*) alloc((size_t)RB * 8);
    // inverted index (spatial)
    int*   cntr_s = (int*)  alloc((size_t)RS * 4);
    int*   off_s  = (int*)  alloc((size_t)RS * 4);
    int*   fill_s = (int*)  alloc((size_t)RS * 4);
    int2*  epw_s  = (int2*) alloc((size_t)RS * 8);
    float* norm_b = (float*)alloc((size_t)NPIX * 4);
    float* norm_s = (float*)alloc((size_t)NPIX * 4);
    float4* Qp  = (float4*)alloc((size_t)NPIX * CP4 * 16);
    float4* fbp = (float4*)alloc((size_t)NPIX * CP4 * 16);
    float4* fsp = (float4*)alloc((size_t)NPIX * CP4 * 16);
    float4* buf0 = (float4*)alloc((size_t)(RB + 1) * CP4 * 16);
    float4* buf1 = (float4*)alloc((size_t)(RB + 1) * CP4 * 16);
    if (off > ws_size) return;  // insufficient scratch -> visible as validation failure

    const float ALPHA_B = (float)(1.0 / (1.0 + exp2(-(double)DB)));  // 32/33
    const float ALPHA_S = (float)(1.0 / (1.0 + exp2(-(double)DS)));  // 4/5

    constexpr int PG = 4096;  // persistent grid blocks for grid-stride kernels

    hipMemsetAsync(cnt, 0, 16, stream);

    // ---- build bilateral lattice ----
    hipMemsetAsync(hk, 0xFF, (size_t)TBS * 8, stream);
    hipMemsetAsync(cntr_b, 0, (size_t)RB * 4, stream);
    hipMemsetAsync(fill_b, 0, (size_t)RB * 4, stream);
    hipMemsetAsync(hist, 0, (size_t)NBUCK * 4, stream);
    hipMemsetAsync(histFill, 0, (size_t)NBUCK * 4, stream);
    build_bilateral<<<(NPIX + 255) / 256, 256, 0, stream>>>(image, hk, TBS - 1, os_b, ws_b);
    // bucket-sorted compaction: ids ordered by (c0,c1) -> blur neighbors nearby
    hist_keys<<<TBS / 256, 256, 0, stream>>>(hk, hist, TBS);
    scan_wave_partial<<<NBUCK / 256, 256, 0, stream>>>(hist, histOff, wsums, NBUCK);
    scan_partials_excl<<<1, 256, 0, stream>>>(wsums, NBUCK / 64, cnt + 0);
    scan_finalize<<<NBUCK / 256, 256, 0, stream>>>(histOff, hist, wsums, NBUCK);
    assign_ids<<<TBS / 256, 256, 0, stream>>>(hk, hid, histOff, histFill, uk_b, TBS);
    os_count_fused<<<(RB + 255) / 256, 256, 0, stream>>>(os_b, hid, cntr_b, RB);
    build_neighbors<DB><<<(RB + 255) / 256, 256, 0, stream>>>(uk_b, hk, hid, TBS - 1, cnt + 0, RB, n1_b, n2_b);
    // ordered exclusive offsets for the inverted index
    scan_wave_partial<<<RB / 256, 256, 0, stream>>>(cntr_b, off_b, wsums, RB);
    scan_partials_excl<<<1, 256, 0, stream>>>(wsums, RB / 64, nullptr);
    scan_finalize<<<RB / 256, 256, 0, stream>>>(off_b, cntr_b, wsums, RB);
    fill_entries<DB1><<<(RB + 255) / 256, 256, 0, stream>>>(os_b, ws_b, off_b, fill_b, epw_b, RB);

    // ---- build spatial lattice (reuse hash region, smaller table) ----
    hipMemsetAsync(hk, 0xFF, (size_t)TSS * 8, stream);
    hipMemsetAsync(cntr_s, 0, (size_t)RS * 4, stream);
    hipMemsetAsync(fill_s, 0, (size_t)RS * 4, stream);
    hipMemsetAsync(hist, 0, (size_t)NBUCK * 4, stream);
    hipMemsetAsync(histFill, 0, (size_t)NBUCK * 4, stream);
    build_spatial<<<(NPIX + 255) / 256, 256, 0, stream>>>(hk, TSS - 1, os_s, ws_s);
    hist_keys<<<TSS / 256, 256, 0, stream>>>(hk, hist, TSS);
    scan_wave_partial<<<NBUCK / 256, 256, 0, stream>>>(hist, histOff, wsums, NBUCK);
    scan_partials_excl<<<1, 256, 0, stream>>>(wsums, NBUCK / 64, cnt + 1);
    scan_finalize<<<NBUCK / 256, 256, 0, stream>>>(histOff, hist, wsums, NBUCK);
    assign_ids<<<TSS / 256, 256, 0, stream>>>(hk, hid, histOff, histFill, uk_s, TSS);
    os_count_fused<<<(RS + 255) / 256, 256, 0, stream>>>(os_s, hid, cntr_s, RS);
    build_neighbors<DS><<<(RS + 255) / 256, 256, 0, stream>>>(uk_s, hk, hid, TSS - 1, cnt + 1, RS, n1_s, n2_s);
    scan_wave_partial<<<RS / 256, 256, 0, stream>>>(cntr_s, off_s, wsums, RS);
    scan_partials_excl<<<1, 256, 0, stream>>>(wsums, RS / 64, nullptr);
    scan_finalize<<<RS / 256, 256, 0, stream>>>(off_s, cntr_s, wsums, RS);
    fill_entries<DS1><<<(RS + 255) / 256, 256, 0, stream>>>(os_s, ws_s, off_s, fill_s, epw_s, RS);

    // ---- norm filters (C=1), computed once ----
    {
        float* nb0 = (float*)buf0; float* nb1 = (float*)buf1;
        gather_splat1<<<1024, 256, 0, stream>>>(off_b, cntr_b, epw_b, nb0, cnt + 0);
        float* a = nb0; float* b = nb1;
        for (int j = 0; j < DB1; j++) {
            blur1<<<1024, 256, 0, stream>>>(a, b, n1_b + (size_t)j * RB, n2_b + (size_t)j * RB, cnt + 0);
            float* t = a; a = b; b = t;
        }
        slice_norm<DB1><<<(NPIX + 255) / 256, 256, 0, stream>>>(a, os_b, ws_b, norm_b, ALPHA_B);

        gather_splat1<<<1024, 256, 0, stream>>>(off_s, cntr_s, epw_s, nb0, cnt + 1);
        a = nb0; b = nb1;
        for (int j = 0; j < DS1; j++) {
            blur1<<<1024, 256, 0, stream>>>(a, b, n1_s + (size_t)j * RS, n2_s + (size_t)j * RS, cnt + 1);
            float* t = a; a = b; b = t;
        }
        slice_norm<DS1><<<(NPIX + 255) / 256, 256, 0, stream>>>(a, os_s, ws_s, norm_s, ALPHA_S);
    }

    // ---- Q0 = softmax(-U) ----
    update_q<<<(NPIX + 255) / 256, 256, 0, stream>>>(U, fbp, fsp, norm_b, norm_s, Q, Qp, 0);

    // ---- 5 mean-field iterations ----
    for (int it = 0; it < 5; it++) {
        // bilateral filter of Qp -> fbp
        gather_splat4<<<PG, 256, 0, stream>>>(Qp, off_b, cntr_b, epw_b, buf0, cnt + 0);
        float4* a = buf0; float4* b = buf1;
        for (int j = 0; j < DB1; j++) {
            blur4<<<PG, 256, 0, stream>>>(a, b, n1_b + (size_t)j * RB, n2_b + (size_t)j * RB, cnt + 0);
            float4* t = a; a = b; b = t;
        }
        slice4<DB1><<<(NPIX * CP4 + 255) / 256, 256, 0, stream>>>(a, os_b, ws_b, fbp, ALPHA_B);

        // spatial filter of Qp -> fsp
        gather_splat4<<<PG, 256, 0, stream>>>(Qp, off_s, cntr_s, epw_s, buf0, cnt + 1);
        a = buf0; b = buf1;
        for (int j = 0; j < DS1; j++) {
            blur4<<<PG, 256, 0, stream>>>(a, b, n1_s + (size_t)j * RS, n2_s + (size_t)j * RS, cnt + 1);
            float4* t = a; a = b; b = t;
        }
        slice4<DS1><<<(NPIX * CP4 + 255) / 256, 256, 0, stream>>>(a, os_s, ws_s, fsp, ALPHA_S);

        // Q = softmax(-U + 10*fb/norm_b + 3*fs/norm_s)
        update_q<<<(NPIX + 255) / 256, 256, 0, stream>>>(U, fbp, fsp, norm_b, norm_s, Q, Qp, 1);
    }
}